// Round 1
// baseline (585.923 us; speedup 1.0000x reference)
//
#include <hip/hip_runtime.h>

// Problem constants
#define N_     8
#define C_     16
#define T_     300
#define F_     257
#define CC_    256            // C*C
#define TF_    (T_*F_)        // 77100
#define CTF_   (C_*TF_)       // 1233600
#define N2CTF_ (2*CTF_)       // per-batch stride in floats (re+im planes)

// K1 tiling
#define FT_    32             // f-tile width
#define NFT_   9              // ceil(257/32)
#define TS_    5              // t's staged per LDS stage
#define RST_   35             // LDS row stride in float2 (odd-ish pad -> bank-safe)
#define ROWS_  85             // 5*16 y-rows + 5 x0-rows

#define LOADC  7.0710678118654755e-04f   // 0.001/sqrt(2)

__device__ __forceinline__ float2 cmul(float2 a, float2 b) {
  return make_float2(a.x*b.x - a.y*b.y, a.x*b.y + a.y*b.x);
}
__device__ __forceinline__ float2 cmulc(float2 a, float2 b) { // a * conj(b)
  return make_float2(a.x*b.x + a.y*b.y, a.y*b.x - a.x*b.y);
}
__device__ __forceinline__ float2 cdiv(float2 a, float2 b) {
  float inv = 1.0f / (b.x*b.x + b.y*b.y);
  return make_float2((a.x*b.x + a.y*b.y)*inv, (a.y*b.x - a.x*b.y)*inv);
}
__device__ __forceinline__ float2 cadd(float2 a, float2 b){ return make_float2(a.x+b.x, a.y+b.y); }
__device__ __forceinline__ float2 csub(float2 a, float2 b){ return make_float2(a.x-b.x, a.y-b.y); }

// ---------------------------------------------------------------------------
// K1: partial covariance + partial cross sums.
// grid (NFT_, TCP, N_), block 128 = 32 f-lanes x 4 groups (2c-halves x 2d-halves)
// Each thread: 8x8 complex accumulator (c0..c0+7) x (d0..d0+7) for its f.
// Writes phi_p[tc][n][f][c*16+d], syx_p/sy_p[tc][n][f][c], sx_p[tc][n][f].
// ---------------------------------------------------------------------------
template<int TCH>
__global__ __launch_bounds__(128, 2) void k1_cov(const float* __restrict__ mix,
                                                 const float* __restrict__ tgt,
                                                 float2* __restrict__ phi_p,
                                                 float2* __restrict__ syx_p,
                                                 float2* __restrict__ sy_p,
                                                 float2* __restrict__ sx_p) {
  __shared__ float2 ys[ROWS_*RST_];
  const int tid = threadIdx.x;
  const int ft = blockIdx.x, tc = blockIdx.y, n = blockIdx.z;
  const int fbase = ft * FT_;
  const int t0 = tc * TCH;
  const int fl = tid & 31;
  const int g  = tid >> 5;          // 0..3 ; wave0={g0,g1}, wave1={g2,g3}
  const int c0 = (g & 1) * 8;
  const int d0 = (g >> 1) * 8;
  const bool sThread = (g < 2);     // wave-uniform: wave0 accumulates S-terms

  float2 acc[8][8];
  #pragma unroll
  for (int i = 0; i < 8; ++i)
    #pragma unroll
    for (int j = 0; j < 8; ++j) acc[i][j] = make_float2(0.f, 0.f);
  float2 syx[8], sy[8], sx = make_float2(0.f, 0.f);
  #pragma unroll
  for (int i = 0; i < 8; ++i) { syx[i] = make_float2(0.f,0.f); sy[i] = make_float2(0.f,0.f); }

  const float* mixN = mix + n * N2CTF_;
  const float* tgtN = tgt + n * N2CTF_;

  for (int stg = 0; stg < TCH / TS_; ++stg) {
    const int tS = t0 + stg * TS_;
    __syncthreads();
    // stage 5 t's of all 16 channels (+x0) into LDS as interleaved complex.
    // 2720 complex elems = (80 y-rows + 5 x-rows) * 32 f. Scalar b32 loads
    // (F=257 odd -> rows unaligned for float4), lanes on consecutive f.
    for (int k = 0; k < 22; ++k) {
      int q = tid + 128 * k;
      if (q < 2720) {
        int row = q >> 5, flq = q & 31;
        const float* src;
        if (row < 80) {
          int ts = row >> 4, c = row & 15;
          src = mixN + c * TF_ + (tS + ts) * F_ + fbase + flq;
        } else {
          int ts = row - 80;
          src = tgtN + (tS + ts) * F_ + fbase + flq;   // channel 0 of target
        }
        float re = 0.f, im = 0.f;
        if (fbase + flq < F_) { re = src[0]; im = src[CTF_]; }
        ys[row * RST_ + flq] = make_float2(re, im);
      }
    }
    __syncthreads();
    #pragma unroll
    for (int tl = 0; tl < TS_; ++tl) {
      const int rb = tl * 16;
      float2 a[8], b[8];
      #pragma unroll
      for (int i = 0; i < 8; ++i) a[i] = ys[(rb + c0 + i) * RST_ + fl];
      #pragma unroll
      for (int j = 0; j < 8; ++j) b[j] = ys[(rb + d0 + j) * RST_ + fl];
      #pragma unroll
      for (int i = 0; i < 8; ++i)
        #pragma unroll
        for (int j = 0; j < 8; ++j) {
          // phi[c,d] += y_c * conj(y_d)
          acc[i][j].x += a[i].x * b[j].x + a[i].y * b[j].y;
          acc[i][j].y += a[i].y * b[j].x - a[i].x * b[j].y;
        }
      if (sThread) {
        float2 xv = ys[(80 + tl) * RST_ + fl];
        #pragma unroll
        for (int i = 0; i < 8; ++i) {
          syx[i].x += a[i].x * xv.x + a[i].y * xv.y;   // y_c * conj(x0)
          syx[i].y += a[i].y * xv.x - a[i].x * xv.y;
          sy[i].x += a[i].x; sy[i].y += a[i].y;
        }
        if (g == 0) { sx.x += xv.x; sx.y += xv.y; }
      }
    }
  }

  const int f = fbase + fl;
  if (f < F_) {
    const int tcn = tc * N_ + n;
    float2* pb = phi_p + ((size_t)tcn * F_ + f) * CC_;
    #pragma unroll
    for (int i = 0; i < 8; ++i) {
      float2* p = pb + (c0 + i) * 16 + d0;   // 8 consecutive float2 = 64B chunk
      #pragma unroll
      for (int j = 0; j < 8; ++j) p[j] = acc[i][j];
    }
    if (sThread) {
      float2* s1 = syx_p + ((size_t)tcn * F_ + f) * C_ + c0;
      float2* s2 = sy_p  + ((size_t)tcn * F_ + f) * C_ + c0;
      #pragma unroll
      for (int i = 0; i < 8; ++i) { s1[i] = syx[i]; s2[i] = sy[i]; }
      if (g == 0) sx_p[(size_t)tcn * F_ + f] = sx;
    }
  }
}

// ---------------------------------------------------------------------------
// K2: reduce partials, build M = sum(y y^H) + T*LOAD*(1+i)*I and
// rhs = T*phi_yx0 (means over batch AND time), Gauss-Jordan solve, write w.
// grid (F_, N_), block 256 = (i,j) element of the 16x16 matrix.
// ---------------------------------------------------------------------------
template<int TCP>
__global__ __launch_bounds__(256) void k2_solve(const float2* __restrict__ phi_p,
                                                const float2* __restrict__ syx_p,
                                                const float2* __restrict__ sy_p,
                                                const float2* __restrict__ sx_p,
                                                float* __restrict__ wre,
                                                float* __restrict__ wim) {
  __shared__ float2 M[16 * 17];   // col 16 = rhs
  __shared__ float2 fac[16];
  __shared__ float2 muA[16];
  __shared__ float2 muB_s, sxO_s;
  const int f = blockIdx.x, n = blockIdx.y;
  const int tid = threadIdx.x;
  const int i = tid >> 4, j = tid & 15;

  // reduce phi partials (coalesced: consecutive tid -> consecutive cd)
  float2 s = make_float2(0.f, 0.f);
  for (int tc = 0; tc < TCP; ++tc) {
    float2 v = phi_p[((size_t)(tc * N_ + n) * F_ + f) * CC_ + tid];
    s.x += v.x; s.y += v.y;
  }
  if (i == j) { s.x += (float)T_ * LOADC; s.y += (float)T_ * LOADC; }
  M[i * 17 + j] = s;

  float2 ownYX = make_float2(0.f,0.f), ownY = make_float2(0.f,0.f);
  if (tid < 16) {
    float2 allY = make_float2(0.f,0.f);
    for (int tc = 0; tc < TCP; ++tc) {
      for (int nn = 0; nn < N_; ++nn) {
        float2 v = sy_p[((size_t)(tc * N_ + nn) * F_ + f) * C_ + tid];
        allY = cadd(allY, v);
        if (nn == n) ownY = cadd(ownY, v);
      }
      ownYX = cadd(ownYX, syx_p[((size_t)(tc * N_ + n) * F_ + f) * C_ + tid]);
    }
    const float invNT = 1.0f / ((float)N_ * (float)T_);
    muA[tid] = make_float2(allY.x * invNT, allY.y * invNT);
  } else if (tid == 16) {
    float2 own = make_float2(0.f,0.f), all = make_float2(0.f,0.f);
    for (int tc = 0; tc < TCP; ++tc)
      for (int nn = 0; nn < N_; ++nn) {
        float2 v = sx_p[(size_t)(tc * N_ + nn) * F_ + f];
        all = cadd(all, v);
        if (nn == n) own = cadd(own, v);
      }
    const float invNT = 1.0f / ((float)N_ * (float)T_);
    muB_s = make_float2(all.x * invNT, all.y * invNT);
    sxO_s = own;
  }
  __syncthreads();
  if (tid < 16) {
    // rhs = S_yx - muA*conj(S_x_own) - conj(muB)*S_y_own + T*muA*conj(muB)
    float2 a = muA[tid];
    float2 r = ownYX;
    r = csub(r, cmulc(a, sxO_s));
    r = csub(r, cmulc(ownY, muB_s));
    float2 t3 = cmulc(a, muB_s);
    r.x += (float)T_ * t3.x; r.y += (float)T_ * t3.y;
    M[tid * 17 + 16] = r;
  }
  __syncthreads();
  // Gauss-Jordan, no pivoting (diag ~600 vs offdiag ~35: strongly dominant)
  for (int k = 0; k < 16; ++k) {
    if (tid < 16) {
      fac[tid] = (tid == k) ? make_float2(0.f,0.f)
                            : cdiv(M[tid * 17 + k], M[k * 17 + k]);
    }
    __syncthreads();
    if (i != k) {
      float2 fi = fac[i];
      M[i * 17 + j] = csub(M[i * 17 + j], cmul(fi, M[k * 17 + j]));
      if (j == 15) M[i * 17 + 16] = csub(M[i * 17 + 16], cmul(fi, M[k * 17 + 16]));
    }
    __syncthreads();
  }
  if (tid < 16) {
    float2 w = cdiv(M[tid * 17 + 16], M[tid * 17 + tid]);
    wre[(n * C_ + tid) * F_ + f] = w.x;
    wim[(n * C_ + tid) * F_ + f] = w.y;
  }
}

// ---------------------------------------------------------------------------
// K3: beamform. Xbf[n,t,f] = sum_c conj(w[n,f,c]) * y[n,c,t,f].
// grid (T_/5, N_), block 256; lanes on f (coalesced), w cached in registers.
// ---------------------------------------------------------------------------
__global__ __launch_bounds__(256) void k3_bf(const float* __restrict__ mix,
                                             const float* __restrict__ wre,
                                             const float* __restrict__ wim,
                                             float* __restrict__ out) {
  const int tg = blockIdx.x, n = blockIdx.y;
  const int t0 = tg * 5;
  const float* mixN = mix + n * N2CTF_;
  const float* wR = wre + n * C_ * F_;
  const float* wI = wim + n * C_ * F_;
  float* outN = out + n * 2 * TF_;
  for (int f = threadIdx.x; f < F_; f += 256) {
    float wr[16], wi[16];
    #pragma unroll
    for (int c = 0; c < 16; ++c) { wr[c] = wR[c * F_ + f]; wi[c] = wI[c * F_ + f]; }
    for (int tt = 0; tt < 5; ++tt) {
      int t = t0 + tt;
      const float* yb = mixN + t * F_ + f;
      float xr = 0.f, xi = 0.f;
      #pragma unroll
      for (int c = 0; c < 16; ++c) {
        float yr = yb[c * TF_];
        float yi = yb[CTF_ + c * TF_];
        xr += wr[c] * yr + wi[c] * yi;   // conj(w)*y
        xi += wr[c] * yi - wi[c] * yr;
      }
      outN[t * F_ + f] = xr;
      outN[TF_ + t * F_ + f] = xi;
    }
  }
}

// ---------------------------------------------------------------------------
template<int TCP>
static void launch_all(const float* mix, const float* tgt, float* ws, float* out,
                       hipStream_t stream) {
  constexpr int TCH = T_ / TCP;
  static_assert(TCH * TCP == T_ && TCH % TS_ == 0, "chunking");
  float2* phi_p = (float2*)ws;
  float2* syx_p = phi_p + (size_t)TCP * N_ * F_ * CC_;
  float2* sy_p  = syx_p + (size_t)TCP * N_ * F_ * C_;
  float2* sx_p  = sy_p  + (size_t)TCP * N_ * F_ * C_;
  float*  wre   = (float*)(sx_p + (size_t)TCP * N_ * F_);
  float*  wim   = wre + N_ * C_ * F_;
  k1_cov<TCH><<<dim3(NFT_, TCP, N_), dim3(128), 0, stream>>>(mix, tgt, phi_p, syx_p, sy_p, sx_p);
  k2_solve<TCP><<<dim3(F_, N_), dim3(256), 0, stream>>>(phi_p, syx_p, sy_p, sx_p, wre, wim);
  k3_bf<<<dim3(T_ / 5, N_), dim3(256), 0, stream>>>(mix, wre, wim, out);
}

static size_t ws_need_bytes(int tcp) {
  // floats: tcp*N*F*(2*CC + 2*C + 2*C + 2) + 2*N*C*F
  size_t fl = (size_t)tcp * N_ * F_ * (2*CC_ + 2*C_ + 2*C_ + 2) + 2ull * N_ * C_ * F_;
  return fl * 4;
}

extern "C" void kernel_launch(void* const* d_in, const int* in_sizes, int n_in,
                              void* d_out, int out_size, void* d_ws, size_t ws_size,
                              hipStream_t stream) {
  const float* mix = (const float*)d_in[0];
  const float* tgt = (const float*)d_in[1];
  // d_in[2] (steering_vector) is unused by the reference.
  float* out = (float*)d_out;
  float* ws  = (float*)d_ws;
  if (ws_size >= ws_need_bytes(6))      launch_all<6>(mix, tgt, ws, out, stream);
  else if (ws_size >= ws_need_bytes(2)) launch_all<2>(mix, tgt, ws, out, stream);
  else                                  launch_all<1>(mix, tgt, ws, out, stream);
}

// Round 3
// 340.790 us; speedup vs baseline: 1.7193x; 1.7193x over previous
//
#include <hip/hip_runtime.h>

// Problem constants
#define N_     8
#define C_     16
#define T_     300
#define F_     257
#define CC_    256            // C*C
#define TF_    (T_*F_)        // 77100
#define CTF_   (C_*TF_)       // 1233600
#define N2CTF_ (2*CTF_)       // per-batch stride in floats (re+im planes)

// K1 tiling
#define FT_    32             // f-tile width
#define NFT_   9              // ceil(257/32)
#define TS_    5              // t's staged per LDS stage
#define RST_   35             // LDS row stride in float2 (bank-safe; 0 conflicts measured R1)
#define ROWS_  85             // 5*16 y-rows + 5 x0-rows

#define LOADC  7.0710678118654755e-04f   // 0.001/sqrt(2)

__device__ __forceinline__ float2 cmul(float2 a, float2 b) {
  return make_float2(a.x*b.x - a.y*b.y, a.x*b.y + a.y*b.x);
}
__device__ __forceinline__ float2 cmulc(float2 a, float2 b) { // a * conj(b)
  return make_float2(a.x*b.x + a.y*b.y, a.y*b.x - a.x*b.y);
}
__device__ __forceinline__ float2 cdiv(float2 a, float2 b) {
  float inv = 1.0f / (b.x*b.x + b.y*b.y);
  return make_float2((a.x*b.x + a.y*b.y)*inv, (a.y*b.x - a.x*b.y)*inv);
}
__device__ __forceinline__ float2 cadd(float2 a, float2 b){ return make_float2(a.x+b.x, a.y+b.y); }
__device__ __forceinline__ float2 csub(float2 a, float2 b){ return make_float2(a.x-b.x, a.y-b.y); }

// ---------------------------------------------------------------------------
// K1: partial covariance + partial cross sums.
// grid (NFT_, TCP, N_), block 256 = 32 f-lanes x 8 groups.
// Group g: c0=(g&1)*8, d0=(g>>1)*4 -> per-thread 8x4 complex acc = 64 VGPRs
// (R1's 8x8 = 128 VGPRs spilled: FETCH/WRITE ~235 MB scratch traffic).
// Writes phi_p[tc][n][f][c*16+d], syx_p/sy_p[tc][n][f][c], sx_p[tc][n][f].
// ---------------------------------------------------------------------------
template<int TCH>
__global__ __launch_bounds__(256, 1) void k1_cov(const float* __restrict__ mix,
                                                 const float* __restrict__ tgt,
                                                 float2* __restrict__ phi_p,
                                                 float2* __restrict__ syx_p,
                                                 float2* __restrict__ sy_p,
                                                 float2* __restrict__ sx_p) {
  __shared__ float2 ys[ROWS_*RST_];
  const int tid = threadIdx.x;
  const int ft = blockIdx.x, tc = blockIdx.y, n = blockIdx.z;
  const int fbase = ft * FT_;
  const int t0 = tc * TCH;
  const int fl = tid & 31;
  const int g  = tid >> 5;          // 0..7
  const int c0 = (g & 1) * 8;
  const int d0 = (g >> 1) * 4;
  const bool sThread = (g < 2);     // wave 0 only (wave-uniform predicate)

  float2 acc[8][4];
  #pragma unroll
  for (int i = 0; i < 8; ++i)
    #pragma unroll
    for (int j = 0; j < 4; ++j) acc[i][j] = make_float2(0.f, 0.f);
  float2 syx[8], sy[8], sx = make_float2(0.f, 0.f);
  #pragma unroll
  for (int i = 0; i < 8; ++i) { syx[i] = make_float2(0.f,0.f); sy[i] = make_float2(0.f,0.f); }

  const float* mixN = mix + n * N2CTF_;
  const float* tgtN = tgt + n * N2CTF_;

  for (int stg = 0; stg < TCH / TS_; ++stg) {
    const int tS = t0 + stg * TS_;
    __syncthreads();
    // stage 5 t's of all 16 channels (+x0) into LDS as interleaved complex.
    // 2720 complex elems; scalar b32 loads (F=257 odd -> no 16B alignment),
    // lanes on consecutive f -> coalesced.
    for (int k = 0; k < 11; ++k) {
      int q = tid + 256 * k;
      if (q < 2720) {
        int row = q >> 5, flq = q & 31;
        const float* src;
        if (row < 80) {
          int ts = row >> 4, c = row & 15;
          src = mixN + c * TF_ + (tS + ts) * F_ + fbase + flq;
        } else {
          int ts = row - 80;
          src = tgtN + (tS + ts) * F_ + fbase + flq;   // channel 0 of target
        }
        float re = 0.f, im = 0.f;
        if (fbase + flq < F_) { re = src[0]; im = src[CTF_]; }
        ys[row * RST_ + flq] = make_float2(re, im);
      }
    }
    __syncthreads();
    #pragma unroll
    for (int tl = 0; tl < TS_; ++tl) {
      const int rb = tl * 16;
      float2 a[8], b[4];
      #pragma unroll
      for (int i = 0; i < 8; ++i) a[i] = ys[(rb + c0 + i) * RST_ + fl];
      #pragma unroll
      for (int j = 0; j < 4; ++j) b[j] = ys[(rb + d0 + j) * RST_ + fl];
      #pragma unroll
      for (int i = 0; i < 8; ++i)
        #pragma unroll
        for (int j = 0; j < 4; ++j) {
          // phi[c,d] += y_c * conj(y_d)
          acc[i][j].x += a[i].x * b[j].x + a[i].y * b[j].y;
          acc[i][j].y += a[i].y * b[j].x - a[i].x * b[j].y;
        }
      if (sThread) {
        float2 xv = ys[(80 + tl) * RST_ + fl];
        #pragma unroll
        for (int i = 0; i < 8; ++i) {
          syx[i].x += a[i].x * xv.x + a[i].y * xv.y;   // y_c * conj(x0)
          syx[i].y += a[i].y * xv.x - a[i].x * xv.y;
          sy[i].x += a[i].x; sy[i].y += a[i].y;
        }
        if (g == 0) { sx.x += xv.x; sx.y += xv.y; }
      }
    }
  }

  const int f = fbase + fl;
  if (f < F_) {
    const int tcn = tc * N_ + n;
    float2* pb = phi_p + ((size_t)tcn * F_ + f) * CC_;
    #pragma unroll
    for (int i = 0; i < 8; ++i) {
      float2* p = pb + (c0 + i) * 16 + d0;   // 4 consecutive float2 = 32B chunk
      #pragma unroll
      for (int j = 0; j < 4; ++j) p[j] = acc[i][j];
    }
    if (sThread) {
      float2* s1 = syx_p + ((size_t)tcn * F_ + f) * C_ + c0;
      float2* s2 = sy_p  + ((size_t)tcn * F_ + f) * C_ + c0;
      #pragma unroll
      for (int i = 0; i < 8; ++i) { s1[i] = syx[i]; s2[i] = sy[i]; }
      if (g == 0) sx_p[(size_t)tcn * F_ + f] = sx;
    }
  }
}

// ---------------------------------------------------------------------------
// K2: reduce partials, build M = sum(y y^H) + T*LOAD*(1+i)*I and
// rhs = T*phi_yx0 (means over batch AND time), Gauss-Jordan solve, write w.
// grid (F_, N_), block 256 = (i,j) element of the 16x16 matrix.
// ALL __syncthreads() are executed unconditionally by all 256 threads
// (R2 put one inside a tid<16 branch -> wave-0 barrier-count mismatch ->
// absmax 394).
// ---------------------------------------------------------------------------
template<int TCP>
__global__ __launch_bounds__(256) void k2_solve(const float2* __restrict__ phi_p,
                                                const float2* __restrict__ syx_p,
                                                const float2* __restrict__ sy_p,
                                                const float2* __restrict__ sx_p,
                                                float* __restrict__ wre,
                                                float* __restrict__ wim) {
  __shared__ float2 M[16 * 17];   // col 16 = rhs
  __shared__ float2 fac[16];
  __shared__ float2 ld_sy[TCP * N_ * C_];
  __shared__ float2 ld_syx[TCP * C_];
  __shared__ float2 ld_sx[TCP * N_];
  __shared__ float2 muB_s, sxO_s;
  const int f = blockIdx.x, n = blockIdx.y;
  const int tid = threadIdx.x;
  const int i = tid >> 4, j = tid & 15;

  // reduce phi partials (coalesced: consecutive tid -> consecutive cd)
  float2 s = make_float2(0.f, 0.f);
  for (int tc = 0; tc < TCP; ++tc) {
    float2 v = phi_p[((size_t)(tc * N_ + n) * F_ + f) * CC_ + tid];
    s.x += v.x; s.y += v.y;
  }
  if (i == j) { s.x += (float)T_ * LOADC; s.y += (float)T_ * LOADC; }
  M[i * 17 + j] = s;

  // stage the small partial sums into LDS (parallel, coalesced-ish runs)
  for (int idx = tid; idx < TCP * N_ * C_; idx += 256) {
    int tcn = idx >> 4, c = idx & 15;
    ld_sy[idx] = sy_p[((size_t)tcn * F_ + f) * C_ + c];
  }
  for (int idx = tid; idx < TCP * C_; idx += 256) {
    int tc = idx >> 4, c = idx & 15;
    ld_syx[idx] = syx_p[((size_t)(tc * N_ + n) * F_ + f) * C_ + c];
  }
  for (int idx = tid; idx < TCP * N_; idx += 256) {
    ld_sx[idx] = sx_p[(size_t)idx * F_ + f];
  }
  __syncthreads();   // uniform

  // per-thread (tid<16) sums stay in registers; only muB_s/sxO_s cross lanes
  float2 muA_r = make_float2(0.f,0.f), ownY = make_float2(0.f,0.f), ownYX = make_float2(0.f,0.f);
  if (tid < 16) {
    float2 allY = make_float2(0.f,0.f);
    for (int tcn = 0; tcn < TCP * N_; ++tcn) allY = cadd(allY, ld_sy[tcn * C_ + tid]);
    for (int tc = 0; tc < TCP; ++tc) {
      ownY  = cadd(ownY,  ld_sy[(tc * N_ + n) * C_ + tid]);
      ownYX = cadd(ownYX, ld_syx[tc * C_ + tid]);
    }
    const float invNT = 1.0f / ((float)N_ * (float)T_);
    muA_r = make_float2(allY.x * invNT, allY.y * invNT);
  }
  if (tid == 16) {
    float2 own = make_float2(0.f,0.f), all = make_float2(0.f,0.f);
    for (int tc = 0; tc < TCP; ++tc)
      for (int nn = 0; nn < N_; ++nn) {
        float2 v = ld_sx[tc * N_ + nn];
        all = cadd(all, v);
        if (nn == n) own = cadd(own, v);
      }
    const float invNT = 1.0f / ((float)N_ * (float)T_);
    muB_s = make_float2(all.x * invNT, all.y * invNT);
    sxO_s = own;
  }
  __syncthreads();   // uniform: publish muB_s/sxO_s

  if (tid < 16) {
    // rhs = S_yx - muA*conj(S_x_own) - conj(muB)*S_y_own + T*muA*conj(muB)
    float2 r = ownYX;
    r = csub(r, cmulc(muA_r, sxO_s));
    r = csub(r, cmulc(ownY, muB_s));
    float2 t3 = cmulc(muA_r, muB_s);
    r.x += (float)T_ * t3.x; r.y += (float)T_ * t3.y;
    M[tid * 17 + 16] = r;
  }
  __syncthreads();   // uniform

  // Gauss-Jordan, no pivoting (diag ~600 vs offdiag ~35: strongly dominant)
  for (int k = 0; k < 16; ++k) {
    if (tid < 16) {
      fac[tid] = (tid == k) ? make_float2(0.f,0.f)
                            : cdiv(M[tid * 17 + k], M[k * 17 + k]);
    }
    __syncthreads();
    if (i != k) {
      float2 fi = fac[i];
      M[i * 17 + j] = csub(M[i * 17 + j], cmul(fi, M[k * 17 + j]));
      if (j == 15) M[i * 17 + 16] = csub(M[i * 17 + 16], cmul(fi, M[k * 17 + 16]));
    }
    __syncthreads();
  }
  if (tid < 16) {
    float2 w = cdiv(M[tid * 17 + 16], M[tid * 17 + tid]);
    wre[(n * C_ + tid) * F_ + f] = w.x;
    wim[(n * C_ + tid) * F_ + f] = w.y;
  }
}

// ---------------------------------------------------------------------------
// K3: beamform. Xbf[n,t,f] = sum_c conj(w[n,f,c]) * y[n,c,t,f].
// grid (T_/5, N_), block 256; lanes on f (coalesced), w cached in registers.
// ---------------------------------------------------------------------------
__global__ __launch_bounds__(256) void k3_bf(const float* __restrict__ mix,
                                             const float* __restrict__ wre,
                                             const float* __restrict__ wim,
                                             float* __restrict__ out) {
  const int tg = blockIdx.x, n = blockIdx.y;
  const int t0 = tg * 5;
  const float* mixN = mix + n * N2CTF_;
  const float* wR = wre + n * C_ * F_;
  const float* wI = wim + n * C_ * F_;
  float* outN = out + n * 2 * TF_;
  for (int f = threadIdx.x; f < F_; f += 256) {
    float wr[16], wi[16];
    #pragma unroll
    for (int c = 0; c < 16; ++c) { wr[c] = wR[c * F_ + f]; wi[c] = wI[c * F_ + f]; }
    for (int tt = 0; tt < 5; ++tt) {
      int t = t0 + tt;
      const float* yb = mixN + t * F_ + f;
      float xr = 0.f, xi = 0.f;
      #pragma unroll
      for (int c = 0; c < 16; ++c) {
        float yr = yb[c * TF_];
        float yi = yb[CTF_ + c * TF_];
        xr += wr[c] * yr + wi[c] * yi;   // conj(w)*y
        xi += wr[c] * yi - wi[c] * yr;
      }
      outN[t * F_ + f] = xr;
      outN[TF_ + t * F_ + f] = xi;
    }
  }
}

// ---------------------------------------------------------------------------
template<int TCP>
static void launch_all(const float* mix, const float* tgt, float* ws, float* out,
                       hipStream_t stream) {
  constexpr int TCH = T_ / TCP;
  static_assert(TCH * TCP == T_ && TCH % TS_ == 0, "chunking");
  float2* phi_p = (float2*)ws;
  float2* syx_p = phi_p + (size_t)TCP * N_ * F_ * CC_;
  float2* sy_p  = syx_p + (size_t)TCP * N_ * F_ * C_;
  float2* sx_p  = sy_p  + (size_t)TCP * N_ * F_ * C_;
  float*  wre   = (float*)(sx_p + (size_t)TCP * N_ * F_);
  float*  wim   = wre + N_ * C_ * F_;
  k1_cov<TCH><<<dim3(NFT_, TCP, N_), dim3(256), 0, stream>>>(mix, tgt, phi_p, syx_p, sy_p, sx_p);
  k2_solve<TCP><<<dim3(F_, N_), dim3(256), 0, stream>>>(phi_p, syx_p, sy_p, sx_p, wre, wim);
  k3_bf<<<dim3(T_ / 5, N_), dim3(256), 0, stream>>>(mix, wre, wim, out);
}

static size_t ws_need_bytes(int tcp) {
  // floats: tcp*N*F*(2*CC + 2*C + 2*C + 2) + 2*N*C*F
  size_t fl = (size_t)tcp * N_ * F_ * (2*CC_ + 2*C_ + 2*C_ + 2) + 2ull * N_ * C_ * F_;
  return fl * 4;
}

extern "C" void kernel_launch(void* const* d_in, const int* in_sizes, int n_in,
                              void* d_out, int out_size, void* d_ws, size_t ws_size,
                              hipStream_t stream) {
  const float* mix = (const float*)d_in[0];
  const float* tgt = (const float*)d_in[1];
  // d_in[2] (steering_vector) is unused by the reference.
  float* out = (float*)d_out;
  float* ws  = (float*)d_ws;
  if (ws_size >= ws_need_bytes(12))      launch_all<12>(mix, tgt, ws, out, stream);
  else if (ws_size >= ws_need_bytes(6))  launch_all<6>(mix, tgt, ws, out, stream);
  else if (ws_size >= ws_need_bytes(2))  launch_all<2>(mix, tgt, ws, out, stream);
  else                                   launch_all<1>(mix, tgt, ws, out, stream);
}

// Round 4
// 267.324 us; speedup vs baseline: 2.1918x; 1.2748x over previous
//
#include <hip/hip_runtime.h>

// Problem constants
#define N_     8
#define C_     16
#define T_     300
#define F_     257
#define CC_    256            // C*C
#define TF_    (T_*F_)        // 77100
#define CTF_   (C_*TF_)       // 1233600
#define N2CTF_ (2*CTF_)       // per-batch stride in floats (re+im planes)

// K1 tiling
#define FT_    32             // f-tile width
#define NFT_   9              // ceil(257/32)
#define TS_    5              // t's staged per LDS stage
#define RST_   35             // LDS row stride in float2 (bank-safe; 0 conflicts measured)
#define SROWS_ 88             // 80 y-rows + 5 x-rows + 3 pad
#define SCNT_  (SROWS_*RST_)  // float2 per buffer

#define LOADC  7.0710678118654755e-04f   // 0.001/sqrt(2)

__device__ __forceinline__ float2 cmul(float2 a, float2 b) {
  return make_float2(a.x*b.x - a.y*b.y, a.x*b.y + a.y*b.x);
}
__device__ __forceinline__ float2 cmulc(float2 a, float2 b) { // a * conj(b)
  return make_float2(a.x*b.x + a.y*b.y, a.y*b.x - a.x*b.y);
}
__device__ __forceinline__ float2 cdiv(float2 a, float2 b) {
  float inv = 1.0f / (b.x*b.x + b.y*b.y);
  return make_float2((a.x*b.x + a.y*b.y)*inv, (a.y*b.x - a.x*b.y)*inv);
}
__device__ __forceinline__ float2 cadd(float2 a, float2 b){ return make_float2(a.x+b.x, a.y+b.y); }
__device__ __forceinline__ float2 csub(float2 a, float2 b){ return make_float2(a.x-b.x, a.y-b.y); }

// ---------------------------------------------------------------------------
// K1 v3: partial covariance + cross sums, software-pipelined.
// grid (NFT_, TCP, N_), block 512 = 32 f-lanes x 16 groups.
// Group g: c0=(g&3)*4, d0=(g>>2)*4 -> 4x4 complex acc = 32 VGPRs (R3's 8x4
// = 64 acc VGPRs gave 144 total -> 3 waves/SIMD; target <=128 -> 4-5).
// Double-buffered LDS: stage s+1 global loads issue into registers BEFORE
// compute of stage s, ds_write after -> VMEM latency hidden under FMAs.
// Staging decode is branch-free: k=0..4 are exactly the 80 y-rows
// (row=16k+srow, c=srow, ts=k), k=5 (waves 0-3 only) the 5 x-rows.
// f OOB handled by address clamp; garbage stays in lanes that never store.
// ---------------------------------------------------------------------------
template<int TCH>
__global__ __launch_bounds__(512, 1) void k1_cov(const float* __restrict__ mix,
                                                 const float* __restrict__ tgt,
                                                 float2* __restrict__ phi_p,
                                                 float2* __restrict__ syx_p,
                                                 float2* __restrict__ sy_p,
                                                 float2* __restrict__ sx_p) {
  __shared__ float2 ys[2][SCNT_];
  const int tid = threadIdx.x;
  const int ft = blockIdx.x, tc = blockIdx.y, n = blockIdx.z;
  const int fbase = ft * FT_;
  const int t0 = tc * TCH;
  const int fl = tid & 31;
  const int g  = tid >> 5;          // 0..15
  const int c0 = (g & 3) * 4;
  const int d0 = (g >> 2) * 4;
  const bool sThread = (g < 4);     // waves 0-1 (uniform); c0 covers 0,4,8,12
  const bool xLoader = (tid < 256); // waves 0-3 (uniform)

  const float* mixN = mix + n * N2CTF_;
  const float* tgtN = tgt + n * N2CTF_;

  // staging constants
  const int srow = tid >> 5;                  // y: channel; x: row-in-x-block
  const int f_ld = min(fbase + fl, F_ - 1);   // clamped OOB f
  const float* ybase = mixN + srow * TF_ + f_ld;
  const int xts = min(srow, TS_ - 1);         // rows 85-87 duplicate t, never read
  const float* xbase = tgtN + f_ld;

  float2 acc[4][4];
  #pragma unroll
  for (int i = 0; i < 4; ++i)
    #pragma unroll
    for (int j = 0; j < 4; ++j) acc[i][j] = make_float2(0.f, 0.f);
  float2 syx[4], sy[4], sx = make_float2(0.f, 0.f);
  #pragma unroll
  for (int i = 0; i < 4; ++i) { syx[i] = make_float2(0.f,0.f); sy[i] = make_float2(0.f,0.f); }

  float lr[6], li[6];
  // prologue: load + write stage 0
  {
    #pragma unroll
    for (int k = 0; k < TS_; ++k) {
      const float* p = ybase + (t0 + k) * F_;
      lr[k] = p[0]; li[k] = p[CTF_];
    }
    if (xLoader) { const float* p = xbase + (t0 + xts) * F_; lr[5] = p[0]; li[5] = p[CTF_]; }
    #pragma unroll
    for (int k = 0; k < TS_; ++k)
      ys[0][(k * 16 + srow) * RST_ + fl] = make_float2(lr[k], li[k]);
    if (xLoader) ys[0][(80 + srow) * RST_ + fl] = make_float2(lr[5], li[5]);
  }

  constexpr int NS = TCH / TS_;
  for (int stg = 0; stg < NS; ++stg) {
    __syncthreads();                 // buf[stg&1] ready; prev compute done
    const bool more = (stg + 1 < NS);
    if (more) {                      // issue next-stage loads (overlap compute)
      const int tS = t0 + (stg + 1) * TS_;
      #pragma unroll
      for (int k = 0; k < TS_; ++k) {
        const float* p = ybase + (tS + k) * F_;
        lr[k] = p[0]; li[k] = p[CTF_];
      }
      if (xLoader) { const float* p = xbase + (tS + xts) * F_; lr[5] = p[0]; li[5] = p[CTF_]; }
    }
    const float2* buf = ys[stg & 1];
    #pragma unroll
    for (int tl = 0; tl < TS_; ++tl) {
      const int rb = tl * 16;
      float2 a[4], b[4];
      #pragma unroll
      for (int i = 0; i < 4; ++i) a[i] = buf[(rb + c0 + i) * RST_ + fl];
      #pragma unroll
      for (int j = 0; j < 4; ++j) b[j] = buf[(rb + d0 + j) * RST_ + fl];
      #pragma unroll
      for (int i = 0; i < 4; ++i)
        #pragma unroll
        for (int j = 0; j < 4; ++j) {
          acc[i][j].x += a[i].x * b[j].x + a[i].y * b[j].y;   // y_c * conj(y_d)
          acc[i][j].y += a[i].y * b[j].x - a[i].x * b[j].y;
        }
      if (sThread) {
        float2 xv = buf[(80 + tl) * RST_ + fl];
        #pragma unroll
        for (int i = 0; i < 4; ++i) {
          syx[i].x += a[i].x * xv.x + a[i].y * xv.y;          // y_c * conj(x0)
          syx[i].y += a[i].y * xv.x - a[i].x * xv.y;
          sy[i].x += a[i].x; sy[i].y += a[i].y;
        }
        if (g == 0) { sx.x += xv.x; sx.y += xv.y; }
      }
    }
    if (more) {
      float2* nb = ys[(stg + 1) & 1];
      #pragma unroll
      for (int k = 0; k < TS_; ++k)
        nb[(k * 16 + srow) * RST_ + fl] = make_float2(lr[k], li[k]);
      if (xLoader) nb[(80 + srow) * RST_ + fl] = make_float2(lr[5], li[5]);
    }
  }

  const int f = fbase + fl;
  if (f < F_) {
    const int tcn = tc * N_ + n;
    float2* pb = phi_p + ((size_t)tcn * F_ + f) * CC_;
    #pragma unroll
    for (int i = 0; i < 4; ++i) {
      float2* p = pb + (c0 + i) * 16 + d0;   // 4 consecutive float2 = 32B
      #pragma unroll
      for (int j = 0; j < 4; ++j) p[j] = acc[i][j];
    }
    if (sThread) {
      float2* s1 = syx_p + ((size_t)tcn * F_ + f) * C_ + c0;
      float2* s2 = sy_p  + ((size_t)tcn * F_ + f) * C_ + c0;
      #pragma unroll
      for (int i = 0; i < 4; ++i) { s1[i] = syx[i]; s2[i] = sy[i]; }
      if (g == 0) sx_p[(size_t)tcn * F_ + f] = sx;
    }
  }
}

// ---------------------------------------------------------------------------
// K2: reduce partials, build M = sum(y y^H) + T*LOAD*(1+i)*I and
// rhs = T*phi_yx0, Gauss-Jordan solve, write w. Unchanged from R3 (passed);
// all barriers uniform.
// ---------------------------------------------------------------------------
template<int TCP>
__global__ __launch_bounds__(256) void k2_solve(const float2* __restrict__ phi_p,
                                                const float2* __restrict__ syx_p,
                                                const float2* __restrict__ sy_p,
                                                const float2* __restrict__ sx_p,
                                                float* __restrict__ wre,
                                                float* __restrict__ wim) {
  __shared__ float2 M[16 * 17];   // col 16 = rhs
  __shared__ float2 fac[16];
  __shared__ float2 ld_sy[TCP * N_ * C_];
  __shared__ float2 ld_syx[TCP * C_];
  __shared__ float2 ld_sx[TCP * N_];
  __shared__ float2 muB_s, sxO_s;
  const int f = blockIdx.x, n = blockIdx.y;
  const int tid = threadIdx.x;
  const int i = tid >> 4, j = tid & 15;

  float2 s = make_float2(0.f, 0.f);
  for (int tc = 0; tc < TCP; ++tc) {
    float2 v = phi_p[((size_t)(tc * N_ + n) * F_ + f) * CC_ + tid];
    s.x += v.x; s.y += v.y;
  }
  if (i == j) { s.x += (float)T_ * LOADC; s.y += (float)T_ * LOADC; }
  M[i * 17 + j] = s;

  for (int idx = tid; idx < TCP * N_ * C_; idx += 256) {
    int tcn = idx >> 4, c = idx & 15;
    ld_sy[idx] = sy_p[((size_t)tcn * F_ + f) * C_ + c];
  }
  for (int idx = tid; idx < TCP * C_; idx += 256) {
    int tc = idx >> 4, c = idx & 15;
    ld_syx[idx] = syx_p[((size_t)(tc * N_ + n) * F_ + f) * C_ + c];
  }
  for (int idx = tid; idx < TCP * N_; idx += 256) {
    ld_sx[idx] = sx_p[(size_t)idx * F_ + f];
  }
  __syncthreads();   // uniform

  float2 muA_r = make_float2(0.f,0.f), ownY = make_float2(0.f,0.f), ownYX = make_float2(0.f,0.f);
  if (tid < 16) {
    float2 allY = make_float2(0.f,0.f);
    for (int tcn = 0; tcn < TCP * N_; ++tcn) allY = cadd(allY, ld_sy[tcn * C_ + tid]);
    for (int tc = 0; tc < TCP; ++tc) {
      ownY  = cadd(ownY,  ld_sy[(tc * N_ + n) * C_ + tid]);
      ownYX = cadd(ownYX, ld_syx[tc * C_ + tid]);
    }
    const float invNT = 1.0f / ((float)N_ * (float)T_);
    muA_r = make_float2(allY.x * invNT, allY.y * invNT);
  }
  if (tid == 16) {
    float2 own = make_float2(0.f,0.f), all = make_float2(0.f,0.f);
    for (int tc = 0; tc < TCP; ++tc)
      for (int nn = 0; nn < N_; ++nn) {
        float2 v = ld_sx[tc * N_ + nn];
        all = cadd(all, v);
        if (nn == n) own = cadd(own, v);
      }
    const float invNT = 1.0f / ((float)N_ * (float)T_);
    muB_s = make_float2(all.x * invNT, all.y * invNT);
    sxO_s = own;
  }
  __syncthreads();   // uniform: publish muB_s/sxO_s

  if (tid < 16) {
    float2 r = ownYX;
    r = csub(r, cmulc(muA_r, sxO_s));
    r = csub(r, cmulc(ownY, muB_s));
    float2 t3 = cmulc(muA_r, muB_s);
    r.x += (float)T_ * t3.x; r.y += (float)T_ * t3.y;
    M[tid * 17 + 16] = r;
  }
  __syncthreads();   // uniform

  for (int k = 0; k < 16; ++k) {
    if (tid < 16) {
      fac[tid] = (tid == k) ? make_float2(0.f,0.f)
                            : cdiv(M[tid * 17 + k], M[k * 17 + k]);
    }
    __syncthreads();
    if (i != k) {
      float2 fi = fac[i];
      M[i * 17 + j] = csub(M[i * 17 + j], cmul(fi, M[k * 17 + j]));
      if (j == 15) M[i * 17 + 16] = csub(M[i * 17 + 16], cmul(fi, M[k * 17 + 16]));
    }
    __syncthreads();
  }
  if (tid < 16) {
    float2 w = cdiv(M[tid * 17 + 16], M[tid * 17 + tid]);
    wre[(n * C_ + tid) * F_ + f] = w.x;
    wim[(n * C_ + tid) * F_ + f] = w.y;
  }
}

// ---------------------------------------------------------------------------
// K3: beamform. Xbf[n,t,f] = sum_c conj(w[n,f,c]) * y[n,c,t,f].
// t-chunk 3 (was 5) -> 800 blocks = 3.1/CU (was 1.9): more latency hiding
// for +11 MB of w re-reads. Lanes on f (coalesced), w in registers.
// ---------------------------------------------------------------------------
#define TB3_ 3
__global__ __launch_bounds__(256) void k3_bf(const float* __restrict__ mix,
                                             const float* __restrict__ wre,
                                             const float* __restrict__ wim,
                                             float* __restrict__ out) {
  const int tg = blockIdx.x, n = blockIdx.y;
  const int t0 = tg * TB3_;
  const float* mixN = mix + n * N2CTF_;
  const float* wR = wre + n * C_ * F_;
  const float* wI = wim + n * C_ * F_;
  float* outN = out + n * 2 * TF_;
  for (int f = threadIdx.x; f < F_; f += 256) {
    float wr[16], wi[16];
    #pragma unroll
    for (int c = 0; c < 16; ++c) { wr[c] = wR[c * F_ + f]; wi[c] = wI[c * F_ + f]; }
    #pragma unroll
    for (int tt = 0; tt < TB3_; ++tt) {
      int t = t0 + tt;
      const float* yb = mixN + t * F_ + f;
      float xr = 0.f, xi = 0.f;
      #pragma unroll
      for (int c = 0; c < 16; ++c) {
        float yr = yb[c * TF_];
        float yi = yb[CTF_ + c * TF_];
        xr += wr[c] * yr + wi[c] * yi;   // conj(w)*y
        xi += wr[c] * yi - wi[c] * yr;
      }
      outN[t * F_ + f] = xr;
      outN[TF_ + t * F_ + f] = xi;
    }
  }
}

// ---------------------------------------------------------------------------
template<int TCP>
static void launch_all(const float* mix, const float* tgt, float* ws, float* out,
                       hipStream_t stream) {
  constexpr int TCH = T_ / TCP;
  static_assert(TCH * TCP == T_ && TCH % TS_ == 0, "chunking");
  float2* phi_p = (float2*)ws;
  float2* syx_p = phi_p + (size_t)TCP * N_ * F_ * CC_;
  float2* sy_p  = syx_p + (size_t)TCP * N_ * F_ * C_;
  float2* sx_p  = sy_p  + (size_t)TCP * N_ * F_ * C_;
  float*  wre   = (float*)(sx_p + (size_t)TCP * N_ * F_);
  float*  wim   = wre + N_ * C_ * F_;
  k1_cov<TCH><<<dim3(NFT_, TCP, N_), dim3(512), 0, stream>>>(mix, tgt, phi_p, syx_p, sy_p, sx_p);
  k2_solve<TCP><<<dim3(F_, N_), dim3(256), 0, stream>>>(phi_p, syx_p, sy_p, sx_p, wre, wim);
  k3_bf<<<dim3(T_ / TB3_, N_), dim3(256), 0, stream>>>(mix, wre, wim, out);
}

static size_t ws_need_bytes(int tcp) {
  size_t fl = (size_t)tcp * N_ * F_ * (2*CC_ + 2*C_ + 2*C_ + 2) + 2ull * N_ * C_ * F_;
  return fl * 4;
}

extern "C" void kernel_launch(void* const* d_in, const int* in_sizes, int n_in,
                              void* d_out, int out_size, void* d_ws, size_t ws_size,
                              hipStream_t stream) {
  const float* mix = (const float*)d_in[0];
  const float* tgt = (const float*)d_in[1];
  // d_in[2] (steering_vector) is unused by the reference.
  float* out = (float*)d_out;
  float* ws  = (float*)d_ws;
  if (ws_size >= ws_need_bytes(12))      launch_all<12>(mix, tgt, ws, out, stream);
  else if (ws_size >= ws_need_bytes(6))  launch_all<6>(mix, tgt, ws, out, stream);
  else if (ws_size >= ws_need_bytes(2))  launch_all<2>(mix, tgt, ws, out, stream);
  else                                   launch_all<1>(mix, tgt, ws, out, stream);
}

// Round 5
// 251.989 us; speedup vs baseline: 2.3252x; 1.0609x over previous
//
#include <hip/hip_runtime.h>

// Problem constants
#define N_     8
#define C_     16
#define T_     300
#define F_     257
#define CC_    256            // C*C
#define TF_    (T_*F_)        // 77100
#define CTF_   (C_*TF_)       // 1233600
#define N2CTF_ (2*CTF_)       // per-batch stride in floats (re+im planes)

// K1 tiling
#define FT_    32             // f-tile width
#define NFT_   9              // ceil(257/32)
#define TS_    5              // t's staged per LDS stage
#define RST_   35             // LDS row stride in float2 (bank-safe; 0 conflicts measured)
#define SROWS_ 88             // 80 y-rows + 5 x-rows + 3 pad
#define SCNT_  (SROWS_*RST_)  // float2 per buffer

#define MREC_  272            // packed M record: 256 matrix + 16 rhs (float2)

#define LOADC  7.0710678118654755e-04f   // 0.001/sqrt(2)

__device__ __forceinline__ float2 cmul(float2 a, float2 b) {
  return make_float2(a.x*b.x - a.y*b.y, a.x*b.y + a.y*b.x);
}
__device__ __forceinline__ float2 cmulc(float2 a, float2 b) { // a * conj(b)
  return make_float2(a.x*b.x + a.y*b.y, a.y*b.x - a.x*b.y);
}
__device__ __forceinline__ float2 cdiv(float2 a, float2 b) {
  float inv = 1.0f / (b.x*b.x + b.y*b.y);
  return make_float2((a.x*b.x + a.y*b.y)*inv, (a.y*b.x - a.x*b.y)*inv);
}
__device__ __forceinline__ float2 cadd(float2 a, float2 b){ return make_float2(a.x+b.x, a.y+b.y); }
__device__ __forceinline__ float2 csub(float2 a, float2 b){ return make_float2(a.x-b.x, a.y-b.y); }

// ---------------------------------------------------------------------------
// K1 v3 (unchanged from R4; 90 us, FETCH/WRITE at ideal, latency-bound):
// partial covariance + cross sums, software-pipelined double-buffered LDS.
// ---------------------------------------------------------------------------
template<int TCH>
__global__ __launch_bounds__(512, 1) void k1_cov(const float* __restrict__ mix,
                                                 const float* __restrict__ tgt,
                                                 float2* __restrict__ phi_p,
                                                 float2* __restrict__ syx_p,
                                                 float2* __restrict__ sy_p,
                                                 float2* __restrict__ sx_p) {
  __shared__ float2 ys[2][SCNT_];
  const int tid = threadIdx.x;
  const int ft = blockIdx.x, tc = blockIdx.y, n = blockIdx.z;
  const int fbase = ft * FT_;
  const int t0 = tc * TCH;
  const int fl = tid & 31;
  const int g  = tid >> 5;          // 0..15
  const int c0 = (g & 3) * 4;
  const int d0 = (g >> 2) * 4;
  const bool sThread = (g < 4);     // waves 0-1 (uniform); c0 covers 0,4,8,12
  const bool xLoader = (tid < 256); // waves 0-3 (uniform)

  const float* mixN = mix + n * N2CTF_;
  const float* tgtN = tgt + n * N2CTF_;

  const int srow = tid >> 5;                  // y: channel; x: row-in-x-block
  const int f_ld = min(fbase + fl, F_ - 1);   // clamped OOB f
  const float* ybase = mixN + srow * TF_ + f_ld;
  const int xts = min(srow, TS_ - 1);         // rows 85-87 duplicate t, never read
  const float* xbase = tgtN + f_ld;

  float2 acc[4][4];
  #pragma unroll
  for (int i = 0; i < 4; ++i)
    #pragma unroll
    for (int j = 0; j < 4; ++j) acc[i][j] = make_float2(0.f, 0.f);
  float2 syx[4], sy[4], sx = make_float2(0.f, 0.f);
  #pragma unroll
  for (int i = 0; i < 4; ++i) { syx[i] = make_float2(0.f,0.f); sy[i] = make_float2(0.f,0.f); }

  float lr[6], li[6];
  {
    #pragma unroll
    for (int k = 0; k < TS_; ++k) {
      const float* p = ybase + (t0 + k) * F_;
      lr[k] = p[0]; li[k] = p[CTF_];
    }
    if (xLoader) { const float* p = xbase + (t0 + xts) * F_; lr[5] = p[0]; li[5] = p[CTF_]; }
    #pragma unroll
    for (int k = 0; k < TS_; ++k)
      ys[0][(k * 16 + srow) * RST_ + fl] = make_float2(lr[k], li[k]);
    if (xLoader) ys[0][(80 + srow) * RST_ + fl] = make_float2(lr[5], li[5]);
  }

  constexpr int NS = TCH / TS_;
  for (int stg = 0; stg < NS; ++stg) {
    __syncthreads();
    const bool more = (stg + 1 < NS);
    if (more) {
      const int tS = t0 + (stg + 1) * TS_;
      #pragma unroll
      for (int k = 0; k < TS_; ++k) {
        const float* p = ybase + (tS + k) * F_;
        lr[k] = p[0]; li[k] = p[CTF_];
      }
      if (xLoader) { const float* p = xbase + (tS + xts) * F_; lr[5] = p[0]; li[5] = p[CTF_]; }
    }
    const float2* buf = ys[stg & 1];
    #pragma unroll
    for (int tl = 0; tl < TS_; ++tl) {
      const int rb = tl * 16;
      float2 a[4], b[4];
      #pragma unroll
      for (int i = 0; i < 4; ++i) a[i] = buf[(rb + c0 + i) * RST_ + fl];
      #pragma unroll
      for (int j = 0; j < 4; ++j) b[j] = buf[(rb + d0 + j) * RST_ + fl];
      #pragma unroll
      for (int i = 0; i < 4; ++i)
        #pragma unroll
        for (int j = 0; j < 4; ++j) {
          acc[i][j].x += a[i].x * b[j].x + a[i].y * b[j].y;   // y_c * conj(y_d)
          acc[i][j].y += a[i].y * b[j].x - a[i].x * b[j].y;
        }
      if (sThread) {
        float2 xv = buf[(80 + tl) * RST_ + fl];
        #pragma unroll
        for (int i = 0; i < 4; ++i) {
          syx[i].x += a[i].x * xv.x + a[i].y * xv.y;          // y_c * conj(x0)
          syx[i].y += a[i].y * xv.x - a[i].x * xv.y;
          sy[i].x += a[i].x; sy[i].y += a[i].y;
        }
        if (g == 0) { sx.x += xv.x; sx.y += xv.y; }
      }
    }
    if (more) {
      float2* nb = ys[(stg + 1) & 1];
      #pragma unroll
      for (int k = 0; k < TS_; ++k)
        nb[(k * 16 + srow) * RST_ + fl] = make_float2(lr[k], li[k]);
      if (xLoader) nb[(80 + srow) * RST_ + fl] = make_float2(lr[5], li[5]);
    }
  }

  const int f = fbase + fl;
  if (f < F_) {
    const int tcn = tc * N_ + n;
    float2* pb = phi_p + ((size_t)tcn * F_ + f) * CC_;
    #pragma unroll
    for (int i = 0; i < 4; ++i) {
      float2* p = pb + (c0 + i) * 16 + d0;
      #pragma unroll
      for (int j = 0; j < 4; ++j) p[j] = acc[i][j];
    }
    if (sThread) {
      float2* s1 = syx_p + ((size_t)tcn * F_ + f) * C_ + c0;
      float2* s2 = sy_p  + ((size_t)tcn * F_ + f) * C_ + c0;
      #pragma unroll
      for (int i = 0; i < 4; ++i) { s1[i] = syx[i]; s2[i] = sy[i]; }
      if (g == 0) sx_p[(size_t)tcn * F_ + f] = sx;
    }
  }
}

// ---------------------------------------------------------------------------
// K2a: streaming reduction only. grid (F_, N_), block 256.
// Reduces phi partials + small sums, builds M (+diag load) and rhs, writes a
// packed 272-float2 record per (n,f) fully coalesced. NO solve here (R4's
// fused kernel trapped a 33-barrier Gauss-Jordan where 240/256 threads idled
// behind every barrier).
// ---------------------------------------------------------------------------
template<int TCP>
__global__ __launch_bounds__(256) void k2a_reduce(const float2* __restrict__ phi_p,
                                                  const float2* __restrict__ syx_p,
                                                  const float2* __restrict__ sy_p,
                                                  const float2* __restrict__ sx_p,
                                                  float2* __restrict__ Mg) {
  __shared__ float2 ld_sy[TCP * N_ * C_];
  __shared__ float2 ld_syx[TCP * C_];
  __shared__ float2 ld_sx[TCP * N_];
  __shared__ float2 muB_s, sxO_s;
  const int f = blockIdx.x, n = blockIdx.y;
  const int tid = threadIdx.x;
  const int i = tid >> 4, j = tid & 15;

  float2 s = make_float2(0.f, 0.f);
  for (int tc = 0; tc < TCP; ++tc) {
    float2 v = phi_p[((size_t)(tc * N_ + n) * F_ + f) * CC_ + tid];
    s.x += v.x; s.y += v.y;
  }
  if (i == j) { s.x += (float)T_ * LOADC; s.y += (float)T_ * LOADC; }

  for (int idx = tid; idx < TCP * N_ * C_; idx += 256) {
    int tcn = idx >> 4, c = idx & 15;
    ld_sy[idx] = sy_p[((size_t)tcn * F_ + f) * C_ + c];
  }
  for (int idx = tid; idx < TCP * C_; idx += 256) {
    int tc = idx >> 4, c = idx & 15;
    ld_syx[idx] = syx_p[((size_t)(tc * N_ + n) * F_ + f) * C_ + c];
  }
  for (int idx = tid; idx < TCP * N_; idx += 256) {
    ld_sx[idx] = sx_p[(size_t)idx * F_ + f];
  }
  __syncthreads();   // uniform

  float2 muA_r = make_float2(0.f,0.f), ownY = make_float2(0.f,0.f), ownYX = make_float2(0.f,0.f);
  if (tid < 16) {
    float2 allY = make_float2(0.f,0.f);
    for (int tcn = 0; tcn < TCP * N_; ++tcn) allY = cadd(allY, ld_sy[tcn * C_ + tid]);
    for (int tc = 0; tc < TCP; ++tc) {
      ownY  = cadd(ownY,  ld_sy[(tc * N_ + n) * C_ + tid]);
      ownYX = cadd(ownYX, ld_syx[tc * C_ + tid]);
    }
    const float invNT = 1.0f / ((float)N_ * (float)T_);
    muA_r = make_float2(allY.x * invNT, allY.y * invNT);
  }
  if (tid == 16) {
    float2 own = make_float2(0.f,0.f), all = make_float2(0.f,0.f);
    for (int tc = 0; tc < TCP; ++tc)
      for (int nn = 0; nn < N_; ++nn) {
        float2 v = ld_sx[tc * N_ + nn];
        all = cadd(all, v);
        if (nn == n) own = cadd(own, v);
      }
    const float invNT = 1.0f / ((float)N_ * (float)T_);
    muB_s = make_float2(all.x * invNT, all.y * invNT);
    sxO_s = own;
  }
  __syncthreads();   // uniform: publish muB_s/sxO_s

  float2* dst = Mg + (size_t)(n * F_ + f) * MREC_;
  dst[tid] = s;                          // coalesced 2 KB store
  if (tid < 16) {
    // rhs = S_yx - muA*conj(S_x_own) - conj(muB)*S_y_own + T*muA*conj(muB)
    float2 r = ownYX;
    r = csub(r, cmulc(muA_r, sxO_s));
    r = csub(r, cmulc(ownY, muB_s));
    float2 t3 = cmulc(muA_r, muB_s);
    r.x += (float)T_ * t3.x; r.y += (float)T_ * t3.y;
    dst[256 + tid] = r;
  }
}

// ---------------------------------------------------------------------------
// K2b: Gauss-Jordan solve. grid (F_, N_), block 64 = ONE wave: s_barrier in a
// single-wave workgroup is a no-op, so the 2-barriers-per-pivot cost ~only a
// waitcnt. Lane = (row i = tid>>2, col-quad q = tid&3). Input record is 2 KB,
// L2-hot (written by k2a just before). No pivoting (diag-dominant).
// ---------------------------------------------------------------------------
__global__ __launch_bounds__(64) void k2b_solve(const float2* __restrict__ Mg,
                                                float* __restrict__ wre,
                                                float* __restrict__ wim) {
  __shared__ float2 M[16 * 17];
  const int f = blockIdx.x, n = blockIdx.y;
  const int tid = threadIdx.x;
  const float2* src = Mg + (size_t)(n * F_ + f) * MREC_;
  #pragma unroll
  for (int r = 0; r < 4; ++r) {
    int idx = tid + 64 * r;            // 0..255 -> (i=idx>>4, j=idx&15)
    M[(idx >> 4) * 17 + (idx & 15)] = src[idx];
  }
  if (tid < 16) M[tid * 17 + 16] = src[256 + tid];
  __syncthreads();

  const int i = tid >> 2, q = tid & 3;
  for (int k = 0; k < 16; ++k) {
    float2 fac = cdiv(M[i * 17 + k], M[k * 17 + k]);  // redundant per row: no fac[] store
    __syncthreads();                   // old M[i][k] read by all before updates
    if (i != k) {
      #pragma unroll
      for (int jj = 0; jj < 4; ++jj) {
        int j = q * 4 + jj;
        M[i * 17 + j] = csub(M[i * 17 + j], cmul(fac, M[k * 17 + j]));
      }
      if (q == 3) M[i * 17 + 16] = csub(M[i * 17 + 16], cmul(fac, M[k * 17 + 16]));
    }
    __syncthreads();                   // row k stable for next pivot
  }
  if (q == 0) {
    float2 w = cdiv(M[i * 17 + 16], M[i * 17 + i]);
    wre[(n * C_ + i) * F_ + f] = w.x;
    wim[(n * C_ + i) * F_ + f] = w.y;
  }
}

// ---------------------------------------------------------------------------
// K3 v3: beamform. grid (T_, N_) = 2400 blocks (was 800): 9.4/CU for latency
// hiding. Lanes on f (coalesced); w register-cached, served from L2/L3
// (w total = 1 MB).
// ---------------------------------------------------------------------------
__global__ __launch_bounds__(256) void k3_bf(const float* __restrict__ mix,
                                             const float* __restrict__ wre,
                                             const float* __restrict__ wim,
                                             float* __restrict__ out) {
  const int t = blockIdx.x, n = blockIdx.y;
  const float* mixN = mix + n * N2CTF_;
  const float* wR = wre + n * C_ * F_;
  const float* wI = wim + n * C_ * F_;
  float* outN = out + n * 2 * TF_;
  for (int f = threadIdx.x; f < F_; f += 256) {
    const float* yb = mixN + t * F_ + f;
    float xr = 0.f, xi = 0.f;
    #pragma unroll
    for (int c = 0; c < 16; ++c) {
      float wr = wR[c * F_ + f], wi = wI[c * F_ + f];
      float yr = yb[c * TF_],    yi = yb[CTF_ + c * TF_];
      xr += wr * yr + wi * yi;   // conj(w)*y
      xi += wr * yi - wi * yr;
    }
    outN[t * F_ + f] = xr;
    outN[TF_ + t * F_ + f] = xi;
  }
}

// ---------------------------------------------------------------------------
template<int TCP>
static void launch_all(const float* mix, const float* tgt, float* ws, float* out,
                       hipStream_t stream) {
  constexpr int TCH = T_ / TCP;
  static_assert(TCH * TCP == T_ && TCH % TS_ == 0, "chunking");
  float2* phi_p = (float2*)ws;
  float2* syx_p = phi_p + (size_t)TCP * N_ * F_ * CC_;
  float2* sy_p  = syx_p + (size_t)TCP * N_ * F_ * C_;
  float2* sx_p  = sy_p  + (size_t)TCP * N_ * F_ * C_;
  float2* Mg    = sx_p  + (size_t)TCP * N_ * F_;
  float*  wre   = (float*)(Mg + (size_t)N_ * F_ * MREC_);
  float*  wim   = wre + N_ * C_ * F_;
  k1_cov<TCH><<<dim3(NFT_, TCP, N_), dim3(512), 0, stream>>>(mix, tgt, phi_p, syx_p, sy_p, sx_p);
  k2a_reduce<TCP><<<dim3(F_, N_), dim3(256), 0, stream>>>(phi_p, syx_p, sy_p, sx_p, Mg);
  k2b_solve<<<dim3(F_, N_), dim3(64), 0, stream>>>(Mg, wre, wim);
  k3_bf<<<dim3(T_, N_), dim3(256), 0, stream>>>(mix, wre, wim, out);
}

static size_t ws_need_bytes(int tcp) {
  size_t fl2 = (size_t)tcp * N_ * F_ * (CC_ + C_ + C_ + 1) + (size_t)N_ * F_ * MREC_;
  return fl2 * 8 + 2ull * N_ * C_ * F_ * 4;
}

extern "C" void kernel_launch(void* const* d_in, const int* in_sizes, int n_in,
                              void* d_out, int out_size, void* d_ws, size_t ws_size,
                              hipStream_t stream) {
  const float* mix = (const float*)d_in[0];
  const float* tgt = (const float*)d_in[1];
  // d_in[2] (steering_vector) is unused by the reference.
  float* out = (float*)d_out;
  float* ws  = (float*)d_ws;
  if (ws_size >= ws_need_bytes(12))      launch_all<12>(mix, tgt, ws, out, stream);
  else if (ws_size >= ws_need_bytes(6))  launch_all<6>(mix, tgt, ws, out, stream);
  else if (ws_size >= ws_need_bytes(2))  launch_all<2>(mix, tgt, ws, out, stream);
  else                                   launch_all<1>(mix, tgt, ws, out, stream);
}

// Round 6
// 240.027 us; speedup vs baseline: 2.4411x; 1.0498x over previous
//
#include <hip/hip_runtime.h>

// Problem constants
#define N_     8
#define C_     16
#define T_     300
#define F_     257
#define TF_    (T_*F_)        // 77100
#define CTF_   (C_*TF_)       // 1233600
#define N2CTF_ (2*CTF_)       // per-batch stride in floats (re+im planes)

// K1 tiling
#define FT_    32             // f-tile width
#define NFT_   9              // ceil(257/32)
#define TS_    5              // t's staged per LDS stage
#define RST_   35             // LDS row stride in float2 (bank-safe; 0 conflicts measured)
#define SROWS_ 88             // 80 y-rows + 5 x-rows + 3 pad
#define SCNT_  (SROWS_*RST_)  // float2 per buffer
#define NTILE_ 10             // lower-triangle 4x4 tiles of the 16x16 Hermitian phi
#define PHIC_  (NTILE_*16)    // 160 float2 stored per (tc,n,f)

#define MREC_  272            // packed M record: 256 matrix + 16 rhs (float2)

#define LOADC  7.0710678118654755e-04f   // 0.001/sqrt(2)

__device__ __forceinline__ float2 cmul(float2 a, float2 b) {
  return make_float2(a.x*b.x - a.y*b.y, a.x*b.y + a.y*b.x);
}
__device__ __forceinline__ float2 cmulc(float2 a, float2 b) { // a * conj(b)
  return make_float2(a.x*b.x + a.y*b.y, a.y*b.x - a.x*b.y);
}
__device__ __forceinline__ float2 cdiv(float2 a, float2 b) {
  float inv = 1.0f / (b.x*b.x + b.y*b.y);
  return make_float2((a.x*b.x + a.y*b.y)*inv, (a.y*b.x - a.x*b.y)*inv);
}
__device__ __forceinline__ float2 cadd(float2 a, float2 b){ return make_float2(a.x+b.x, a.y+b.y); }
__device__ __forceinline__ float2 csub(float2 a, float2 b){ return make_float2(a.x-b.x, a.y-b.y); }

// ---------------------------------------------------------------------------
// K1 v4: Hermitian partial covariance + cross sums, software-pipelined.
// grid (NFT_, TCP, N_), block 320 = 32 f-lanes x 10 groups.
// Group g -> lower-triangle tile (ti,tj), c0=ti*4, d0=tj*4: only 10 of 16
// 4x4 tiles computed (phi Hermitian) -> FMA x0.625, phi traffic 50->26 MB.
// TCP=10 -> 720 blocks <= 768 co-resident (LDS 49.3 KB -> 3 blocks/CU):
// single dispatch round (R5's 864 needed 2 rounds -> ~2x per-block latency).
// Double-buffered LDS, next-stage global loads in registers before compute.
// ---------------------------------------------------------------------------
template<int TCH>
__global__ __launch_bounds__(320, 1) void k1_cov(const float* __restrict__ mix,
                                                 const float* __restrict__ tgt,
                                                 float2* __restrict__ phi_p,
                                                 float2* __restrict__ syx_p,
                                                 float2* __restrict__ sy_p,
                                                 float2* __restrict__ sx_p) {
  __shared__ float2 ys[2][SCNT_];
  const int tid = threadIdx.x;
  const int ft = blockIdx.x, tc = blockIdx.y, n = blockIdx.z;
  const int fbase = ft * FT_;
  const int t0 = tc * TCH;
  const int fl = tid & 31;
  const int g  = tid >> 5;          // 0..9
  // decode lower-triangle tile: g -> (ti,tj), ti>=tj
  int ti = 0, tj = g;
  while (tj > ti) { ++ti; tj -= ti; }
  const int c0 = ti * 4;
  const int d0 = tj * 4;
  const bool sThread = (tj == 0);   // tiles (0..3,0): c0 covers 0,4,8,12
  const bool xg = (g < 5);          // groups 0-4 stage the 5 x-rows

  const float* mixN = mix + n * N2CTF_;
  const float* tgtN = tgt + n * N2CTF_;

  // staging: group g loads y-rows g*8..g*8+7 = (ts=g>>1, c=(g&1)*8+k)
  const int ts_g   = g >> 1;
  const int c_base = (g & 1) * 8;
  const int row0   = ts_g * 16 + c_base;      // LDS row of first staged y
  const int f_ld = min(fbase + fl, F_ - 1);   // clamped OOB f
  const float* ybase = mixN + c_base * TF_ + f_ld;
  const float* xbase = tgtN + f_ld;

  float2 acc[4][4];
  #pragma unroll
  for (int i = 0; i < 4; ++i)
    #pragma unroll
    for (int j = 0; j < 4; ++j) acc[i][j] = make_float2(0.f, 0.f);
  float2 syx[4], sy[4], sx = make_float2(0.f, 0.f);
  #pragma unroll
  for (int i = 0; i < 4; ++i) { syx[i] = make_float2(0.f,0.f); sy[i] = make_float2(0.f,0.f); }

  float lr[9], li[9];
  // prologue: load + write stage 0
  {
    #pragma unroll
    for (int k = 0; k < 8; ++k) {
      const float* p = ybase + k * TF_ + (t0 + ts_g) * F_;
      lr[k] = p[0]; li[k] = p[CTF_];
    }
    if (xg) { const float* p = xbase + (t0 + g) * F_; lr[8] = p[0]; li[8] = p[CTF_]; }
    #pragma unroll
    for (int k = 0; k < 8; ++k)
      ys[0][(row0 + k) * RST_ + fl] = make_float2(lr[k], li[k]);
    if (xg) ys[0][(80 + g) * RST_ + fl] = make_float2(lr[8], li[8]);
  }

  constexpr int NS = TCH / TS_;
  for (int stg = 0; stg < NS; ++stg) {
    __syncthreads();                 // buf[stg&1] ready; prev compute done
    const bool more = (stg + 1 < NS);
    if (more) {                      // issue next-stage loads (overlap compute)
      const int tS = t0 + (stg + 1) * TS_;
      #pragma unroll
      for (int k = 0; k < 8; ++k) {
        const float* p = ybase + k * TF_ + (tS + ts_g) * F_;
        lr[k] = p[0]; li[k] = p[CTF_];
      }
      if (xg) { const float* p = xbase + (tS + g) * F_; lr[8] = p[0]; li[8] = p[CTF_]; }
    }
    const float2* buf = ys[stg & 1];
    #pragma unroll
    for (int tl = 0; tl < TS_; ++tl) {
      const int rb = tl * 16;
      float2 a[4], b[4];
      #pragma unroll
      for (int i = 0; i < 4; ++i) a[i] = buf[(rb + c0 + i) * RST_ + fl];
      #pragma unroll
      for (int j = 0; j < 4; ++j) b[j] = buf[(rb + d0 + j) * RST_ + fl];
      #pragma unroll
      for (int i = 0; i < 4; ++i)
        #pragma unroll
        for (int j = 0; j < 4; ++j) {
          acc[i][j].x += a[i].x * b[j].x + a[i].y * b[j].y;   // y_c * conj(y_d)
          acc[i][j].y += a[i].y * b[j].x - a[i].x * b[j].y;
        }
      if (sThread) {
        float2 xv = buf[(80 + tl) * RST_ + fl];
        #pragma unroll
        for (int i = 0; i < 4; ++i) {
          syx[i].x += a[i].x * xv.x + a[i].y * xv.y;          // y_c * conj(x0)
          syx[i].y += a[i].y * xv.x - a[i].x * xv.y;
          sy[i].x += a[i].x; sy[i].y += a[i].y;
        }
        if (g == 0) { sx.x += xv.x; sx.y += xv.y; }
      }
    }
    if (more) {
      float2* nb = ys[(stg + 1) & 1];
      #pragma unroll
      for (int k = 0; k < 8; ++k)
        nb[(row0 + k) * RST_ + fl] = make_float2(lr[k], li[k]);
      if (xg) nb[(80 + g) * RST_ + fl] = make_float2(lr[8], li[8]);
    }
  }

  const int f = fbase + fl;
  if (f < F_) {
    const int tcn = tc * N_ + n;
    // tile g stored at offset g*16, row-major 4x4 -> 128 B contiguous/lane
    float2* pb = phi_p + ((size_t)tcn * F_ + f) * PHIC_ + g * 16;
    #pragma unroll
    for (int i = 0; i < 4; ++i)
      #pragma unroll
      for (int j = 0; j < 4; ++j) pb[i * 4 + j] = acc[i][j];
    if (sThread) {
      float2* s1 = syx_p + ((size_t)tcn * F_ + f) * C_ + c0;
      float2* s2 = sy_p  + ((size_t)tcn * F_ + f) * C_ + c0;
      #pragma unroll
      for (int i = 0; i < 4; ++i) { s1[i] = syx[i]; s2[i] = sy[i]; }
      if (g == 0) sx_p[(size_t)tcn * F_ + f] = sx;
    }
  }
}

// ---------------------------------------------------------------------------
// K2a: streaming reduction. grid (F_, N_), block 256 = (i,j) of 16x16 M.
// Upper triangle reconstructed from conj of stored lower tiles (L2-resident,
// written by K1 just before). Builds M (+diag load) and rhs, writes packed
// 272-float2 record per (n,f).
// ---------------------------------------------------------------------------
template<int TCP>
__global__ __launch_bounds__(256) void k2a_reduce(const float2* __restrict__ phi_p,
                                                  const float2* __restrict__ syx_p,
                                                  const float2* __restrict__ sy_p,
                                                  const float2* __restrict__ sx_p,
                                                  float2* __restrict__ Mg) {
  __shared__ float2 ld_sy[TCP * N_ * C_];
  __shared__ float2 ld_syx[TCP * C_];
  __shared__ float2 ld_sx[TCP * N_];
  __shared__ float2 muB_s, sxO_s;
  const int f = blockIdx.x, n = blockIdx.y;
  const int tid = threadIdx.x;
  const int i = tid >> 4, j = tid & 15;

  // Hermitian mirror: cell (i,j) lives in tile (ti,tj) if ti>=tj, else
  // conj of cell (j,i) in tile (tj,ti).
  const int ti = i >> 2, tj = j >> 2, ci = i & 3, cj = j & 3;
  int gL, cell; bool cj_flip;
  if (ti >= tj) { gL = ti * (ti + 1) / 2 + tj; cell = ci * 4 + cj; cj_flip = false; }
  else          { gL = tj * (tj + 1) / 2 + ti; cell = cj * 4 + ci; cj_flip = true; }
  const int off = gL * 16 + cell;

  float2 s = make_float2(0.f, 0.f);
  for (int tc = 0; tc < TCP; ++tc) {
    float2 v = phi_p[((size_t)(tc * N_ + n) * F_ + f) * PHIC_ + off];
    s.x += v.x; s.y += v.y;
  }
  if (cj_flip) s.y = -s.y;
  if (i == j) { s.x += (float)T_ * LOADC; s.y += (float)T_ * LOADC; }

  for (int idx = tid; idx < TCP * N_ * C_; idx += 256) {
    int tcn = idx >> 4, c = idx & 15;
    ld_sy[idx] = sy_p[((size_t)tcn * F_ + f) * C_ + c];
  }
  for (int idx = tid; idx < TCP * C_; idx += 256) {
    int tc = idx >> 4, c = idx & 15;
    ld_syx[idx] = syx_p[((size_t)(tc * N_ + n) * F_ + f) * C_ + c];
  }
  for (int idx = tid; idx < TCP * N_; idx += 256) {
    ld_sx[idx] = sx_p[(size_t)idx * F_ + f];
  }
  __syncthreads();   // uniform

  float2 muA_r = make_float2(0.f,0.f), ownY = make_float2(0.f,0.f), ownYX = make_float2(0.f,0.f);
  if (tid < 16) {
    float2 allY = make_float2(0.f,0.f);
    for (int tcn = 0; tcn < TCP * N_; ++tcn) allY = cadd(allY, ld_sy[tcn * C_ + tid]);
    for (int tc = 0; tc < TCP; ++tc) {
      ownY  = cadd(ownY,  ld_sy[(tc * N_ + n) * C_ + tid]);
      ownYX = cadd(ownYX, ld_syx[tc * C_ + tid]);
    }
    const float invNT = 1.0f / ((float)N_ * (float)T_);
    muA_r = make_float2(allY.x * invNT, allY.y * invNT);
  }
  if (tid == 16) {
    float2 own = make_float2(0.f,0.f), all = make_float2(0.f,0.f);
    for (int tc = 0; tc < TCP; ++tc)
      for (int nn = 0; nn < N_; ++nn) {
        float2 v = ld_sx[tc * N_ + nn];
        all = cadd(all, v);
        if (nn == n) own = cadd(own, v);
      }
    const float invNT = 1.0f / ((float)N_ * (float)T_);
    muB_s = make_float2(all.x * invNT, all.y * invNT);
    sxO_s = own;
  }
  __syncthreads();   // uniform: publish muB_s/sxO_s

  float2* dst = Mg + (size_t)(n * F_ + f) * MREC_;
  dst[tid] = s;                          // coalesced 2 KB store
  if (tid < 16) {
    // rhs = S_yx - muA*conj(S_x_own) - conj(muB)*S_y_own + T*muA*conj(muB)
    float2 r = ownYX;
    r = csub(r, cmulc(muA_r, sxO_s));
    r = csub(r, cmulc(ownY, muB_s));
    float2 t3 = cmulc(muA_r, muB_s);
    r.x += (float)T_ * t3.x; r.y += (float)T_ * t3.y;
    dst[256 + tid] = r;
  }
}

// ---------------------------------------------------------------------------
// K2b: Gauss-Jordan solve, one wave per (n,f) (barriers ~free in single-wave
// workgroups). Unchanged from R5 (passed). No pivoting (diag-dominant).
// ---------------------------------------------------------------------------
__global__ __launch_bounds__(64) void k2b_solve(const float2* __restrict__ Mg,
                                                float* __restrict__ wre,
                                                float* __restrict__ wim) {
  __shared__ float2 M[16 * 17];
  const int f = blockIdx.x, n = blockIdx.y;
  const int tid = threadIdx.x;
  const float2* src = Mg + (size_t)(n * F_ + f) * MREC_;
  #pragma unroll
  for (int r = 0; r < 4; ++r) {
    int idx = tid + 64 * r;
    M[(idx >> 4) * 17 + (idx & 15)] = src[idx];
  }
  if (tid < 16) M[tid * 17 + 16] = src[256 + tid];
  __syncthreads();

  const int i = tid >> 2, q = tid & 3;
  for (int k = 0; k < 16; ++k) {
    float2 fac = cdiv(M[i * 17 + k], M[k * 17 + k]);
    __syncthreads();
    if (i != k) {
      #pragma unroll
      for (int jj = 0; jj < 4; ++jj) {
        int j = q * 4 + jj;
        M[i * 17 + j] = csub(M[i * 17 + j], cmul(fac, M[k * 17 + j]));
      }
      if (q == 3) M[i * 17 + 16] = csub(M[i * 17 + 16], cmul(fac, M[k * 17 + 16]));
    }
    __syncthreads();
  }
  if (q == 0) {
    float2 w = cdiv(M[i * 17 + 16], M[i * 17 + i]);
    wre[(n * C_ + i) * F_ + f] = w.x;
    wim[(n * C_ + i) * F_ + f] = w.y;
  }
}

// ---------------------------------------------------------------------------
// K3 v4: beamform, 2 t's per block. grid (T_/2, N_) = 1200 blocks.
// w register-cached and reused for both t's (halves w traffic); 64
// independent y loads in flight per thread (2x MLP vs R5).
// ---------------------------------------------------------------------------
__global__ __launch_bounds__(256) void k3_bf(const float* __restrict__ mix,
                                             const float* __restrict__ wre,
                                             const float* __restrict__ wim,
                                             float* __restrict__ out) {
  const int t0 = blockIdx.x * 2, n = blockIdx.y;
  const float* mixN = mix + n * N2CTF_;
  const float* wR = wre + n * C_ * F_;
  const float* wI = wim + n * C_ * F_;
  float* outN = out + n * 2 * TF_;
  for (int f = threadIdx.x; f < F_; f += 256) {
    float wr[16], wi[16];
    #pragma unroll
    for (int c = 0; c < 16; ++c) { wr[c] = wR[c * F_ + f]; wi[c] = wI[c * F_ + f]; }
    const float* yb = mixN + t0 * F_ + f;
    float xr0 = 0.f, xi0 = 0.f, xr1 = 0.f, xi1 = 0.f;
    #pragma unroll
    for (int c = 0; c < 16; ++c) {
      float yr0 = yb[c * TF_],      yi0 = yb[CTF_ + c * TF_];
      float yr1 = yb[c * TF_ + F_], yi1 = yb[CTF_ + c * TF_ + F_];
      xr0 += wr[c] * yr0 + wi[c] * yi0;   // conj(w)*y
      xi0 += wr[c] * yi0 - wi[c] * yr0;
      xr1 += wr[c] * yr1 + wi[c] * yi1;
      xi1 += wr[c] * yi1 - wi[c] * yr1;
    }
    outN[t0 * F_ + f] = xr0;
    outN[TF_ + t0 * F_ + f] = xi0;
    outN[(t0 + 1) * F_ + f] = xr1;
    outN[TF_ + (t0 + 1) * F_ + f] = xi1;
  }
}

// ---------------------------------------------------------------------------
template<int TCP>
static void launch_all(const float* mix, const float* tgt, float* ws, float* out,
                       hipStream_t stream) {
  constexpr int TCH = T_ / TCP;
  static_assert(TCH * TCP == T_ && TCH % TS_ == 0, "chunking");
  float2* phi_p = (float2*)ws;
  float2* syx_p = phi_p + (size_t)TCP * N_ * F_ * PHIC_;
  float2* sy_p  = syx_p + (size_t)TCP * N_ * F_ * C_;
  float2* sx_p  = sy_p  + (size_t)TCP * N_ * F_ * C_;
  float2* Mg    = sx_p  + (size_t)TCP * N_ * F_;
  float*  wre   = (float*)(Mg + (size_t)N_ * F_ * MREC_);
  float*  wim   = wre + N_ * C_ * F_;
  k1_cov<TCH><<<dim3(NFT_, TCP, N_), dim3(320), 0, stream>>>(mix, tgt, phi_p, syx_p, sy_p, sx_p);
  k2a_reduce<TCP><<<dim3(F_, N_), dim3(256), 0, stream>>>(phi_p, syx_p, sy_p, sx_p, Mg);
  k2b_solve<<<dim3(F_, N_), dim3(64), 0, stream>>>(Mg, wre, wim);
  k3_bf<<<dim3(T_ / 2, N_), dim3(256), 0, stream>>>(mix, wre, wim, out);
}

static size_t ws_need_bytes(int tcp) {
  size_t fl2 = (size_t)tcp * N_ * F_ * (PHIC_ + C_ + C_ + 1) + (size_t)N_ * F_ * MREC_;
  return fl2 * 8 + 2ull * N_ * C_ * F_ * 4;
}

extern "C" void kernel_launch(void* const* d_in, const int* in_sizes, int n_in,
                              void* d_out, int out_size, void* d_ws, size_t ws_size,
                              hipStream_t stream) {
  const float* mix = (const float*)d_in[0];
  const float* tgt = (const float*)d_in[1];
  // d_in[2] (steering_vector) is unused by the reference.
  float* out = (float*)d_out;
  float* ws  = (float*)d_ws;
  if (ws_size >= ws_need_bytes(10))      launch_all<10>(mix, tgt, ws, out, stream);
  else if (ws_size >= ws_need_bytes(5))  launch_all<5>(mix, tgt, ws, out, stream);
  else if (ws_size >= ws_need_bytes(2))  launch_all<2>(mix, tgt, ws, out, stream);
  else                                   launch_all<1>(mix, tgt, ws, out, stream);
}

// Round 7
// 237.801 us; speedup vs baseline: 2.4639x; 1.0094x over previous
//
#include <hip/hip_runtime.h>

// Problem constants
#define N_     8
#define C_     16
#define T_     300
#define F_     257
#define TF_    (T_*F_)        // 77100
#define CTF_   (C_*TF_)       // 1233600
#define N2CTF_ (2*CTF_)       // per-batch stride in floats (re+im planes)

// K1 tiling
#define FT_    32             // f-tile width
#define NFT_   9              // ceil(257/32)
#define TS_    5              // t's staged per LDS stage
#define RST_   35             // LDS row stride in v2f (bank-safe; 0 conflicts measured)
#define SROWS_ 88             // 80 y-rows + 5 x-rows + 3 pad
#define SCNT_  (SROWS_*RST_)  // v2f per (single) buffer = 3080 -> 24.6 KB
#define NTILE_ 10             // lower-triangle 4x4 tiles of the 16x16 Hermitian phi
#define PHIC_  (NTILE_*16)    // 160 float2 stored per (tc,n,f)

#define MREC_  272            // packed M record: 256 matrix + 16 rhs (float2)

#define LOADC  7.0710678118654755e-04f   // 0.001/sqrt(2)

typedef float v2f __attribute__((ext_vector_type(2)));

__device__ __forceinline__ float2 cmul(float2 a, float2 b) {
  return make_float2(a.x*b.x - a.y*b.y, a.x*b.y + a.y*b.x);
}
__device__ __forceinline__ float2 cmulc(float2 a, float2 b) { // a * conj(b)
  return make_float2(a.x*b.x + a.y*b.y, a.y*b.x - a.x*b.y);
}
__device__ __forceinline__ float2 cdiv(float2 a, float2 b) {
  float inv = 1.0f / (b.x*b.x + b.y*b.y);
  return make_float2((a.x*b.x + a.y*b.y)*inv, (a.y*b.x - a.x*b.y)*inv);
}
__device__ __forceinline__ float2 cadd(float2 a, float2 b){ return make_float2(a.x+b.x, a.y+b.y); }
__device__ __forceinline__ float2 csub(float2 a, float2 b){ return make_float2(a.x-b.x, a.y-b.y); }

// ---------------------------------------------------------------------------
// K1 v5: Hermitian partial covariance + cross sums.
// grid (NFT_, TCP, N_), block 320 = 32 f-lanes x 10 lower-triangle groups.
// SINGLE-buffered LDS (24.6 KB; R6's double buffer at 49.3 KB capped
// residency at 3 blocks/CU while VGPR allows 4) with 2 uniform barriers per
// stage; register prefetch of stage s+1 still overlaps compute of stage s.
// Inner loop in v2f packed form: acc += a.x*{b.x,-b.y} + a.y*{b.y,b.x}
// (v_pk_fma_f32 eligible -> ~half the FMA issue of scalar form).
// ---------------------------------------------------------------------------
template<int TCH>
__global__ __launch_bounds__(320, 1) void k1_cov(const float* __restrict__ mix,
                                                 const float* __restrict__ tgt,
                                                 float2* __restrict__ phi_pf,
                                                 float2* __restrict__ syx_pf,
                                                 float2* __restrict__ sy_pf,
                                                 float2* __restrict__ sx_pf) {
  __shared__ v2f ys[SCNT_];
  v2f* phi_p = (v2f*)phi_pf;
  v2f* syx_p = (v2f*)syx_pf;
  v2f* sy_p  = (v2f*)sy_pf;
  v2f* sx_p  = (v2f*)sx_pf;
  const int tid = threadIdx.x;
  const int ft = blockIdx.x, tc = blockIdx.y, n = blockIdx.z;
  const int fbase = ft * FT_;
  const int t0 = tc * TCH;
  const int fl = tid & 31;
  const int g  = tid >> 5;          // 0..9
  int ti = 0, tj = g;               // lower-triangle tile decode, ti>=tj
  while (tj > ti) { ++ti; tj -= ti; }
  const int c0 = ti * 4;
  const int d0 = tj * 4;
  const bool sThread = (tj == 0);   // tiles (0..3,0): c0 covers 0,4,8,12
  const bool xg = (g < 5);          // groups 0-4 stage the 5 x-rows

  const float* mixN = mix + n * N2CTF_;
  const float* tgtN = tgt + n * N2CTF_;

  // staging: group g loads y-rows (ts=g>>1, c=(g&1)*8+k), k=0..7
  const int ts_g   = g >> 1;
  const int c_base = (g & 1) * 8;
  const int row0   = ts_g * 16 + c_base;
  const int f_ld = min(fbase + fl, F_ - 1);   // clamped OOB f
  const float* ybase = mixN + c_base * TF_ + f_ld;
  const float* xbase = tgtN + f_ld;

  v2f acc[4][4];
  #pragma unroll
  for (int i = 0; i < 4; ++i)
    #pragma unroll
    for (int j = 0; j < 4; ++j) acc[i][j] = (v2f){0.f, 0.f};
  v2f syx[4], sy[4], sx = (v2f){0.f, 0.f};
  #pragma unroll
  for (int i = 0; i < 4; ++i) { syx[i] = (v2f){0.f,0.f}; sy[i] = (v2f){0.f,0.f}; }

  float lr[9], li[9];
  // prologue: load + write stage 0
  {
    #pragma unroll
    for (int k = 0; k < 8; ++k) {
      const float* p = ybase + k * TF_ + (t0 + ts_g) * F_;
      lr[k] = p[0]; li[k] = p[CTF_];
    }
    if (xg) { const float* p = xbase + (t0 + g) * F_; lr[8] = p[0]; li[8] = p[CTF_]; }
    #pragma unroll
    for (int k = 0; k < 8; ++k)
      ys[(row0 + k) * RST_ + fl] = (v2f){lr[k], li[k]};
    if (xg) ys[(80 + g) * RST_ + fl] = (v2f){lr[8], li[8]};
  }

  constexpr int NS = TCH / TS_;
  for (int stg = 0; stg < NS; ++stg) {
    __syncthreads();                 // stage stg writes visible (uniform)
    const bool more = (stg + 1 < NS);
    if (more) {                      // issue next-stage loads (overlap compute)
      const int tS = t0 + (stg + 1) * TS_;
      #pragma unroll
      for (int k = 0; k < 8; ++k) {
        const float* p = ybase + k * TF_ + (tS + ts_g) * F_;
        lr[k] = p[0]; li[k] = p[CTF_];
      }
      if (xg) { const float* p = xbase + (tS + g) * F_; lr[8] = p[0]; li[8] = p[CTF_]; }
    }
    #pragma unroll
    for (int tl = 0; tl < TS_; ++tl) {
      const int rb = tl * 16;
      v2f a[4], bu[4], bv[4];
      #pragma unroll
      for (int i = 0; i < 4; ++i) a[i] = ys[(rb + c0 + i) * RST_ + fl];
      #pragma unroll
      for (int j = 0; j < 4; ++j) {
        v2f b = ys[(rb + d0 + j) * RST_ + fl];
        bu[j] = (v2f){b.x, -b.y};            // for y_c * conj(y_d)
        bv[j] = (v2f){b.y,  b.x};
      }
      #pragma unroll
      for (int i = 0; i < 4; ++i)
        #pragma unroll
        for (int j = 0; j < 4; ++j)
          acc[i][j] += a[i].x * bu[j] + a[i].y * bv[j];
      if (sThread) {
        v2f xv = ys[(80 + tl) * RST_ + fl];
        v2f xu = (v2f){xv.x, -xv.y};
        v2f xw = (v2f){xv.y,  xv.x};
        #pragma unroll
        for (int i = 0; i < 4; ++i) {
          syx[i] += a[i].x * xu + a[i].y * xw;   // y_c * conj(x0)
          sy[i]  += a[i];
        }
        if (g == 0) sx += xv;
      }
    }
    __syncthreads();                 // all readers done before overwrite (uniform)
    if (more) {
      #pragma unroll
      for (int k = 0; k < 8; ++k)
        ys[(row0 + k) * RST_ + fl] = (v2f){lr[k], li[k]};
      if (xg) ys[(80 + g) * RST_ + fl] = (v2f){lr[8], li[8]};
    }
  }

  const int f = fbase + fl;
  if (f < F_) {
    const int tcn = tc * N_ + n;
    // tile g stored at offset g*16, row-major 4x4 -> 128 B contiguous/lane
    v2f* pb = phi_p + ((size_t)tcn * F_ + f) * PHIC_ + g * 16;
    #pragma unroll
    for (int i = 0; i < 4; ++i)
      #pragma unroll
      for (int j = 0; j < 4; ++j) pb[i * 4 + j] = acc[i][j];
    if (sThread) {
      v2f* s1 = syx_p + ((size_t)tcn * F_ + f) * C_ + c0;
      v2f* s2 = sy_p  + ((size_t)tcn * F_ + f) * C_ + c0;
      #pragma unroll
      for (int i = 0; i < 4; ++i) { s1[i] = syx[i]; s2[i] = sy[i]; }
      if (g == 0) sx_p[(size_t)tcn * F_ + f] = sx;
    }
  }
}

// ---------------------------------------------------------------------------
// K2a: streaming reduction. grid (F_, N_), block 256 = (i,j) of 16x16 M.
// Upper triangle reconstructed from conj of stored lower tiles. Builds M
// (+diag load) and rhs, writes packed 272-float2 record per (n,f).
// ---------------------------------------------------------------------------
template<int TCP>
__global__ __launch_bounds__(256) void k2a_reduce(const float2* __restrict__ phi_p,
                                                  const float2* __restrict__ syx_p,
                                                  const float2* __restrict__ sy_p,
                                                  const float2* __restrict__ sx_p,
                                                  float2* __restrict__ Mg) {
  __shared__ float2 ld_sy[TCP * N_ * C_];
  __shared__ float2 ld_syx[TCP * C_];
  __shared__ float2 ld_sx[TCP * N_];
  __shared__ float2 muB_s, sxO_s;
  const int f = blockIdx.x, n = blockIdx.y;
  const int tid = threadIdx.x;
  const int i = tid >> 4, j = tid & 15;

  // Hermitian mirror: (i,j) in lower tile (ti,tj) directly, else conj (j,i).
  const int ti = i >> 2, tj = j >> 2, ci = i & 3, cj = j & 3;
  int gL, cell; bool cj_flip;
  if (ti >= tj) { gL = ti * (ti + 1) / 2 + tj; cell = ci * 4 + cj; cj_flip = false; }
  else          { gL = tj * (tj + 1) / 2 + ti; cell = cj * 4 + ci; cj_flip = true; }
  const int off = gL * 16 + cell;

  float2 s = make_float2(0.f, 0.f);
  for (int tc = 0; tc < TCP; ++tc) {
    float2 v = phi_p[((size_t)(tc * N_ + n) * F_ + f) * PHIC_ + off];
    s.x += v.x; s.y += v.y;
  }
  if (cj_flip) s.y = -s.y;
  if (i == j) { s.x += (float)T_ * LOADC; s.y += (float)T_ * LOADC; }

  for (int idx = tid; idx < TCP * N_ * C_; idx += 256) {
    int tcn = idx >> 4, c = idx & 15;
    ld_sy[idx] = sy_p[((size_t)tcn * F_ + f) * C_ + c];
  }
  for (int idx = tid; idx < TCP * C_; idx += 256) {
    int tc = idx >> 4, c = idx & 15;
    ld_syx[idx] = syx_p[((size_t)(tc * N_ + n) * F_ + f) * C_ + c];
  }
  for (int idx = tid; idx < TCP * N_; idx += 256) {
    ld_sx[idx] = sx_p[(size_t)idx * F_ + f];
  }
  __syncthreads();   // uniform

  float2 muA_r = make_float2(0.f,0.f), ownY = make_float2(0.f,0.f), ownYX = make_float2(0.f,0.f);
  if (tid < 16) {
    float2 allY = make_float2(0.f,0.f);
    for (int tcn = 0; tcn < TCP * N_; ++tcn) allY = cadd(allY, ld_sy[tcn * C_ + tid]);
    for (int tc = 0; tc < TCP; ++tc) {
      ownY  = cadd(ownY,  ld_sy[(tc * N_ + n) * C_ + tid]);
      ownYX = cadd(ownYX, ld_syx[tc * C_ + tid]);
    }
    const float invNT = 1.0f / ((float)N_ * (float)T_);
    muA_r = make_float2(allY.x * invNT, allY.y * invNT);
  }
  if (tid == 16) {
    float2 own = make_float2(0.f,0.f), all = make_float2(0.f,0.f);
    for (int tc = 0; tc < TCP; ++tc)
      for (int nn = 0; nn < N_; ++nn) {
        float2 v = ld_sx[tc * N_ + nn];
        all = cadd(all, v);
        if (nn == n) own = cadd(own, v);
      }
    const float invNT = 1.0f / ((float)N_ * (float)T_);
    muB_s = make_float2(all.x * invNT, all.y * invNT);
    sxO_s = own;
  }
  __syncthreads();   // uniform: publish muB_s/sxO_s

  float2* dst = Mg + (size_t)(n * F_ + f) * MREC_;
  dst[tid] = s;                          // coalesced 2 KB store
  if (tid < 16) {
    // rhs = S_yx - muA*conj(S_x_own) - conj(muB)*S_y_own + T*muA*conj(muB)
    float2 r = ownYX;
    r = csub(r, cmulc(muA_r, sxO_s));
    r = csub(r, cmulc(ownY, muB_s));
    float2 t3 = cmulc(muA_r, muB_s);
    r.x += (float)T_ * t3.x; r.y += (float)T_ * t3.y;
    dst[256 + tid] = r;
  }
}

// ---------------------------------------------------------------------------
// K2b: Gauss-Jordan solve, one wave per (n,f) (barriers ~free single-wave).
// No pivoting (diag-dominant). Unchanged (passed R5/R6).
// ---------------------------------------------------------------------------
__global__ __launch_bounds__(64) void k2b_solve(const float2* __restrict__ Mg,
                                                float* __restrict__ wre,
                                                float* __restrict__ wim) {
  __shared__ float2 M[16 * 17];
  const int f = blockIdx.x, n = blockIdx.y;
  const int tid = threadIdx.x;
  const float2* src = Mg + (size_t)(n * F_ + f) * MREC_;
  #pragma unroll
  for (int r = 0; r < 4; ++r) {
    int idx = tid + 64 * r;
    M[(idx >> 4) * 17 + (idx & 15)] = src[idx];
  }
  if (tid < 16) M[tid * 17 + 16] = src[256 + tid];
  __syncthreads();

  const int i = tid >> 2, q = tid & 3;
  for (int k = 0; k < 16; ++k) {
    float2 fac = cdiv(M[i * 17 + k], M[k * 17 + k]);
    __syncthreads();
    if (i != k) {
      #pragma unroll
      for (int jj = 0; jj < 4; ++jj) {
        int j = q * 4 + jj;
        M[i * 17 + j] = csub(M[i * 17 + j], cmul(fac, M[k * 17 + j]));
      }
      if (q == 3) M[i * 17 + 16] = csub(M[i * 17 + 16], cmul(fac, M[k * 17 + 16]));
    }
    __syncthreads();
  }
  if (q == 0) {
    float2 w = cdiv(M[i * 17 + 16], M[i * 17 + i]);
    wre[(n * C_ + i) * F_ + f] = w.x;
    wim[(n * C_ + i) * F_ + f] = w.y;
  }
}

// ---------------------------------------------------------------------------
// K3 v5: beamform, 2 t's per block. grid (T_/2, N_) = 1200 blocks x 320 thr
// (5 waves) = 23 waves/CU. f = tid single-pass: R6's f-loop made lane 0 of
// wave 0 re-iterate for f=256 with 63 idle lanes (serial tail per block).
// ---------------------------------------------------------------------------
__global__ __launch_bounds__(320) void k3_bf(const float* __restrict__ mix,
                                             const float* __restrict__ wre,
                                             const float* __restrict__ wim,
                                             float* __restrict__ out) {
  const int t0 = blockIdx.x * 2, n = blockIdx.y;
  const int f = threadIdx.x;
  if (f >= F_) return;
  const float* mixN = mix + n * N2CTF_;
  const float* wR = wre + n * C_ * F_;
  const float* wI = wim + n * C_ * F_;
  float* outN = out + n * 2 * TF_;
  float wr[16], wi[16];
  #pragma unroll
  for (int c = 0; c < 16; ++c) { wr[c] = wR[c * F_ + f]; wi[c] = wI[c * F_ + f]; }
  const float* yb = mixN + t0 * F_ + f;
  float xr0 = 0.f, xi0 = 0.f, xr1 = 0.f, xi1 = 0.f;
  #pragma unroll
  for (int c = 0; c < 16; ++c) {
    float yr0 = yb[c * TF_],      yi0 = yb[CTF_ + c * TF_];
    float yr1 = yb[c * TF_ + F_], yi1 = yb[CTF_ + c * TF_ + F_];
    xr0 += wr[c] * yr0 + wi[c] * yi0;   // conj(w)*y
    xi0 += wr[c] * yi0 - wi[c] * yr0;
    xr1 += wr[c] * yr1 + wi[c] * yi1;
    xi1 += wr[c] * yi1 - wi[c] * yr1;
  }
  outN[t0 * F_ + f] = xr0;
  outN[TF_ + t0 * F_ + f] = xi0;
  outN[(t0 + 1) * F_ + f] = xr1;
  outN[TF_ + (t0 + 1) * F_ + f] = xi1;
}

// ---------------------------------------------------------------------------
template<int TCP>
static void launch_all(const float* mix, const float* tgt, float* ws, float* out,
                       hipStream_t stream) {
  constexpr int TCH = T_ / TCP;
  static_assert(TCH * TCP == T_ && TCH % TS_ == 0, "chunking");
  float2* phi_p = (float2*)ws;
  float2* syx_p = phi_p + (size_t)TCP * N_ * F_ * PHIC_;
  float2* sy_p  = syx_p + (size_t)TCP * N_ * F_ * C_;
  float2* sx_p  = sy_p  + (size_t)TCP * N_ * F_ * C_;
  float2* Mg    = sx_p  + (size_t)TCP * N_ * F_;
  float*  wre   = (float*)(Mg + (size_t)N_ * F_ * MREC_);
  float*  wim   = wre + N_ * C_ * F_;
  k1_cov<TCH><<<dim3(NFT_, TCP, N_), dim3(320), 0, stream>>>(mix, tgt, phi_p, syx_p, sy_p, sx_p);
  k2a_reduce<TCP><<<dim3(F_, N_), dim3(256), 0, stream>>>(phi_p, syx_p, sy_p, sx_p, Mg);
  k2b_solve<<<dim3(F_, N_), dim3(64), 0, stream>>>(Mg, wre, wim);
  k3_bf<<<dim3(T_ / 2, N_), dim3(320), 0, stream>>>(mix, wre, wim, out);
}

static size_t ws_need_bytes(int tcp) {
  size_t fl2 = (size_t)tcp * N_ * F_ * (PHIC_ + C_ + C_ + 1) + (size_t)N_ * F_ * MREC_;
  return fl2 * 8 + 2ull * N_ * C_ * F_ * 4;
}

extern "C" void kernel_launch(void* const* d_in, const int* in_sizes, int n_in,
                              void* d_out, int out_size, void* d_ws, size_t ws_size,
                              hipStream_t stream) {
  const float* mix = (const float*)d_in[0];
  const float* tgt = (const float*)d_in[1];
  // d_in[2] (steering_vector) is unused by the reference.
  float* out = (float*)d_out;
  float* ws  = (float*)d_ws;
  if (ws_size >= ws_need_bytes(12))      launch_all<12>(mix, tgt, ws, out, stream);
  else if (ws_size >= ws_need_bytes(10)) launch_all<10>(mix, tgt, ws, out, stream);
  else if (ws_size >= ws_need_bytes(6))  launch_all<6>(mix, tgt, ws, out, stream);
  else if (ws_size >= ws_need_bytes(2))  launch_all<2>(mix, tgt, ws, out, stream);
  else                                   launch_all<1>(mix, tgt, ws, out, stream);
}